// Round 9
// baseline (147.405 us; speedup 1.0000x reference)
//
#include <hip/hip_runtime.h>
#include <hip/hip_bf16.h>

typedef _Float16 half8 __attribute__((ext_vector_type(8)));
typedef _Float16 f16x8 __attribute__((ext_vector_type(8)));
typedef __fp16 fp16x2 __attribute__((ext_vector_type(2)));
typedef float f32x16 __attribute__((ext_vector_type(16)));
typedef unsigned uint2v __attribute__((ext_vector_type(2)));

#define NPIX 16384      // H*W
#define NPOOL 4096      // pooled N
#define BN 32768        // B*N
#define KSPLIT 8
#define LOG2E 1.44269504088896340736f
#define THR 4.0f        // defer-max threshold (log2 units): p <= 2^4, f16-safe

__device__ inline f32x16 mfma16(half8 a, half8 b, f32x16 c) {
  return __builtin_amdgcn_mfma_f32_32x32x16_f16(a, b, c, 0, 0, 0);
}

// ---- K1 (fused prep): theta f16 [BN][8]*log2e; phiT f16 [b][M][8]; gT f16 [b][64][M]
__global__ __launch_bounds__(256) void prep_kernel(
    const float* __restrict__ x,
    const float* __restrict__ w_theta, const float* __restrict__ b_theta,
    const float* __restrict__ w_phi, const float* __restrict__ b_phi,
    const float* __restrict__ w_g, const float* __restrict__ b_g,
    _Float16* __restrict__ qf, _Float16* __restrict__ phiT,
    _Float16* __restrict__ gT) {
  __shared__ float xs[64][256];
  int bid = blockIdx.x;
  int oh = bid & 1;
  int pr = (bid >> 1) & 63;
  int b  = bid >> 7;
  int t = threadIdx.x;

  const float* xb = x + (size_t)b * 64 * NPIX + pr * 256;
#pragma unroll 8
  for (int c = 0; c < 64; c++) xs[c][t] = xb[(size_t)c * NPIX + t];
  __syncthreads();

  if (oh == 0) {
    float acc[8];
#pragma unroll
    for (int j = 0; j < 8; j++) acc[j] = b_theta[j];
    for (int c = 0; c < 64; c++) {
      float xv = xs[c][t];
#pragma unroll
      for (int j = 0; j < 8; j++) acc[j] += xv * w_theta[j * 64 + c];
    }
    half8 h;
#pragma unroll
    for (int j = 0; j < 8; j++) h[j] = (_Float16)(acc[j] * LOG2E);
    *(half8*)(qf + ((size_t)b * NPIX + pr * 256 + t) * 8) = h;
  }

  int pos = t & 63;
  int ocg = t >> 6;
  int oc0 = oh * 36 + ocg * 9;
  const float* wrow[9];
  float a0[9], a1[9], a2[9], a3[9];
#pragma unroll
  for (int j = 0; j < 9; j++) {
    int oc = oc0 + j;
    float bv;
    if (oc < 64) { wrow[j] = w_g + oc * 64; bv = b_g[oc]; }
    else         { wrow[j] = w_phi + (oc - 64) * 64; bv = b_phi[oc - 64]; }
    a0[j] = bv; a1[j] = bv; a2[j] = bv; a3[j] = bv;
  }
  for (int c = 0; c < 64; c++) {
    float2 lo = *(const float2*)&xs[c][2 * pos];
    float2 hi = *(const float2*)&xs[c][128 + 2 * pos];
#pragma unroll
    for (int j = 0; j < 9; j++) {
      float wv = wrow[j][c];
      a0[j] += wv * lo.x;
      a1[j] += wv * lo.y;
      a2[j] += wv * hi.x;
      a3[j] += wv * hi.y;
    }
  }
  int m = pr * 64 + pos;
#pragma unroll
  for (int j = 0; j < 9; j++) {
    int oc = oc0 + j;
    float v = fmaxf(fmaxf(a0[j], a1[j]), fmaxf(a2[j], a3[j]));
    if (oc < 64) gT[((size_t)b * 64 + oc) * NPOOL + m] = (_Float16)v;
    else         phiT[((size_t)b * NPOOL + m) * 8 + (oc - 64)] = (_Float16)v;
  }
}

// ---- K2: flash attention partials, defer-max + prefetched staging ----
// grid = b(2) x qt(128) x kc(8) = 2048 blocks; 4 waves x 32 queries
__global__ __launch_bounds__(256, 4) void attn_kernel(
    const _Float16* __restrict__ qf, const _Float16* __restrict__ phiT,
    const _Float16* __restrict__ gT,
    float* __restrict__ part_m, float* __restrict__ part_l,
    _Float16* __restrict__ part_o) {
  __shared__ _Float16 lds_g[64 * 64];    // [c row][64 keys], XOR-swizzled 16B slots
  int bx = blockIdx.x;
  int kc = bx & (KSPLIT - 1);
  int qt = (bx >> 3) & 127;
  int b  = bx >> 10;
  int tid = threadIdx.x;
  int lane = tid & 63;
  int w = tid >> 6;
  int q = lane & 31, hi = lane >> 5;
  int qg0 = qt * 128 + w * 32;

  half8 qfrag = {0, 0, 0, 0, 0, 0, 0, 0};
  if (!hi) qfrag = *(const half8*)(qf + ((size_t)b * NPIX + qg0 + q) * 8);

  f32x16 oacc0, oacc1;
#pragma unroll
  for (int i = 0; i < 16; i++) { oacc0[i] = 0.f; oacc1[i] = 0.f; }
  float lsum = 0.f;
  float mrun = 0.f, nm = -0.f;           // running max (pair-shared), its negative

  const int NSTEP = (NPOOL / KSPLIT) / 64;   // 8
  int kb0 = kc * (NPOOL / KSPLIT);           // 512-key chunk base

  // staging geometry (constant per thread)
  int c0 = tid >> 3, s0 = tid & 7;
  const _Float16* gsrc0 = gT + ((size_t)b * 64 + c0) * NPOOL + 8 * s0;
  const _Float16* gsrc1 = gsrc0 + (size_t)32 * NPOOL;      // c0+32
  unsigned off0 = c0 * 64 + (((16 * s0) ^ ((c0 & 7) << 4)) >> 1);
  unsigned off1 = (c0 + 32) * 64 + (((16 * s0) ^ ((c0 & 7) << 4)) >> 1);

  // prefetch step 0
  half8 st0 = *(const half8*)(gsrc0 + kb0);
  half8 st1 = *(const half8*)(gsrc1 + kb0);

#pragma unroll 1
  for (int step = 0; step < NSTEP; ++step) {
    int kb = kb0 + step * 64;
    __syncthreads();                     // WAR: all reads of lds_g finished
    *(half8*)(lds_g + off0) = st0;
    *(half8*)(lds_g + off1) = st1;
    int nkb = (step + 1 < NSTEP) ? kb + 64 : kb0;   // clamped prefetch addr
    st0 = *(const half8*)(gsrc0 + nkb);             // in flight under compute
    st1 = *(const half8*)(gsrc1 + nkb);
    // hoist both subs' phi fragments (issue under the barrier)
    half8 aphi0 = {0, 0, 0, 0, 0, 0, 0, 0}, aphi1 = aphi0;
    if (!hi) {
      aphi0 = *(const half8*)(phiT + ((size_t)b * NPOOL + kb + q) * 8);
      aphi1 = *(const half8*)(phiT + ((size_t)b * NPOOL + kb + 32 + q) * 8);
    }
    __syncthreads();                     // RAW: staged tile visible
#pragma unroll
    for (int sub = 0; sub < 2; ++sub) {
      half8 aphi = sub ? aphi1 : aphi0;
      f32x16 sacc;
#pragma unroll
      for (int i = 0; i < 16; i++) sacc[i] = nm;     // C-init = -m_running
      sacc = mfma16(aphi, qfrag, sacc);              // sacc = s - m
      // per-lane max of own 16 relative scores (max3-fusable tree)
      float m01 = fmaxf(fmaxf(sacc[0], sacc[1]), fmaxf(sacc[2], sacc[3]));
      float m23 = fmaxf(fmaxf(sacc[4], sacc[5]), fmaxf(sacc[6], sacc[7]));
      float m45 = fmaxf(fmaxf(sacc[8], sacc[9]), fmaxf(sacc[10], sacc[11]));
      float m67 = fmaxf(fmaxf(sacc[12], sacc[13]), fmaxf(sacc[14], sacc[15]));
      float pm = fmaxf(fmaxf(m01, m23), fmaxf(m45, m67));
      float p[16];
      if (__builtin_expect(!__all(pm <= THR), 0)) {  // rare: raise m, rescale
        float pmp = fmaxf(pm, __shfl_xor(pm, 32));   // pair-shared (only here)
        float d = fmaxf(pmp, 0.f);
        float f = exp2f(-d);
        lsum *= f;
#pragma unroll
        for (int i = 0; i < 16; i++) { oacc0[i] *= f; oacc1[i] *= f; }
        mrun += d; nm = -mrun;
#pragma unroll
        for (int i = 0; i < 16; i++) p[i] = exp2f(sacc[i] - d);
      } else {                                        // common: p in (0, 16]
#pragma unroll
        for (int i = 0; i < 16; i++) p[i] = exp2f(sacc[i]);
      }
#pragma unroll
      for (int halfk = 0; halfk < 2; ++halfk) {
        int pb = halfk * 8;
        fp16x2 h0 = __builtin_amdgcn_cvt_pkrtz(p[pb + 0], p[pb + 1]);
        fp16x2 h1 = __builtin_amdgcn_cvt_pkrtz(p[pb + 2], p[pb + 3]);
        fp16x2 h2 = __builtin_amdgcn_cvt_pkrtz(p[pb + 4], p[pb + 5]);
        fp16x2 h3 = __builtin_amdgcn_cvt_pkrtz(p[pb + 6], p[pb + 7]);
#if __has_builtin(__builtin_amdgcn_fdot2)
        const fp16x2 ones = {(__fp16)1.0f, (__fp16)1.0f};
        lsum = __builtin_amdgcn_fdot2(h0, ones, lsum, false);
        lsum = __builtin_amdgcn_fdot2(h1, ones, lsum, false);
        lsum = __builtin_amdgcn_fdot2(h2, ones, lsum, false);
        lsum = __builtin_amdgcn_fdot2(h3, ones, lsum, false);
#else
        lsum += p[pb + 0] + p[pb + 1] + p[pb + 2] + p[pb + 3];
        lsum += p[pb + 4] + p[pb + 5] + p[pb + 6] + p[pb + 7];
#endif
        unsigned A0 = __builtin_bit_cast(unsigned, h0);
        unsigned A1 = __builtin_bit_cast(unsigned, h1);
        unsigned B0 = __builtin_bit_cast(unsigned, h2);
        unsigned B1 = __builtin_bit_cast(unsigned, h3);
        union { unsigned u[4]; half8 h; } pf;
#if __has_builtin(__builtin_amdgcn_permlane32_swap)
        uint2v r0 = __builtin_amdgcn_permlane32_swap(A0, B0, false, false);
        uint2v r1 = __builtin_amdgcn_permlane32_swap(A1, B1, false, false);
        pf.u[0] = r0[0]; pf.u[1] = r1[0]; pf.u[2] = r0[1]; pf.u[3] = r1[1];
#else
        unsigned xA0 = __shfl_xor(A0, 32), xA1 = __shfl_xor(A1, 32);
        unsigned xB0 = __shfl_xor(B0, 32), xB1 = __shfl_xor(B1, 32);
        pf.u[0] = hi ? xB0 : A0;
        pf.u[1] = hi ? xB1 : A1;
        pf.u[2] = hi ? B0 : xA0;
        pf.u[3] = hi ? B1 : xA1;
#endif
        int sread = sub * 4 + halfk * 2 + hi;
#pragma unroll
        for (int ct = 0; ct < 2; ++ct) {
          int row = ct * 32 + q;
          half8 ag = *(const half8*)(lds_g + row * 64 +
                                     (((16 * sread) ^ ((row & 7) << 4)) >> 1));
          if (ct == 0) oacc0 = mfma16(ag, pf.h, oacc0);
          else         oacc1 = mfma16(ag, pf.h, oacc1);
        }
      }
    }
  }
  lsum += __shfl_xor(lsum, 32);
  if (!hi) {
    part_m[(size_t)kc * BN + b * NPIX + qg0 + q] = mrun;
    part_l[(size_t)kc * BN + b * NPIX + qg0 + q] = lsum;
  }
  // part_o f16 layout [kc][b][n][64]; lane packs 4-channel groups -> 8B stores
  _Float16* po = part_o + (((size_t)(kc * 2 + b) * NPIX) + qg0 + q) * 64;
#pragma unroll
  for (int ct = 0; ct < 2; ++ct) {
#pragma unroll
    for (int g = 0; g < 4; ++g) {
      float v0 = ct ? oacc1[4 * g + 0] : oacc0[4 * g + 0];
      float v1 = ct ? oacc1[4 * g + 1] : oacc0[4 * g + 1];
      float v2 = ct ? oacc1[4 * g + 2] : oacc0[4 * g + 2];
      float v3 = ct ? oacc1[4 * g + 3] : oacc0[4 * g + 3];
      uint2v u;
      u[0] = __builtin_bit_cast(unsigned, __builtin_amdgcn_cvt_pkrtz(v0, v1));
      u[1] = __builtin_bit_cast(unsigned, __builtin_amdgcn_cvt_pkrtz(v2, v3));
      *(uint2v*)(po + 32 * ct + 8 * g + 4 * hi) = u;   // ch = (r&3)+8g+4hi+32ct
    }
  }
}

// ---- K3: combine chunks (max-weighted) + residual epilogue ----
__global__ __launch_bounds__(256) void reduce_kernel(
    const float* __restrict__ part_m, const float* __restrict__ part_l,
    const _Float16* __restrict__ part_o, const float* __restrict__ x,
    const float* __restrict__ sig, float* __restrict__ out) {
  int t = threadIdx.x;
  int cg = t >> 6;                       // 0..3 -> channels cg*16..+15
  int qi = blockIdx.x * 64 + (t & 63);
  int b = qi >> 14, n = qi & (NPIX - 1);
  float mv[KSPLIT], lv[KSPLIT];
  float mstar = -3e38f;
#pragma unroll
  for (int kc = 0; kc < KSPLIT; kc++) {
    mv[kc] = part_m[(size_t)kc * BN + qi];
    lv[kc] = part_l[(size_t)kc * BN + qi];
    mstar = fmaxf(mstar, mv[kc]);
  }
  float wk[KSPLIT], L = 0.f;
#pragma unroll
  for (int kc = 0; kc < KSPLIT; kc++) {
    wk[kc] = exp2f(mv[kc] - mstar);
    L += lv[kc] * wk[kc];
  }
  float o16[16];
#pragma unroll
  for (int j = 0; j < 16; j++) o16[j] = 0.f;
#pragma unroll
  for (int kc = 0; kc < KSPLIT; kc++) {
    const _Float16* po = part_o + (((size_t)(kc * 2 + b) * NPIX) + n) * 64 + cg * 16;
    f16x8 v0 = *(const f16x8*)po;
    f16x8 v1 = *(const f16x8*)(po + 8);
    float wv = wk[kc];
#pragma unroll
    for (int j = 0; j < 8; j++) {
      o16[j]     += wv * (float)v0[j];
      o16[8 + j] += wv * (float)v1[j];
    }
  }
  float scale = sig[0] / L;
#pragma unroll
  for (int j = 0; j < 16; j++) {
    int c = cg * 16 + j;
    size_t idx = ((size_t)b * 64 + c) * NPIX + n;
    out[idx] = x[idx] + scale * o16[j];
  }
}

extern "C" void kernel_launch(void* const* d_in, const int* in_sizes, int n_in,
                              void* d_out, int out_size, void* d_ws, size_t ws_size,
                              hipStream_t stream) {
  const float* x       = (const float*)d_in[0];
  const float* w_theta = (const float*)d_in[1];
  const float* b_theta = (const float*)d_in[2];
  const float* w_phi   = (const float*)d_in[3];
  const float* b_phi   = (const float*)d_in[4];
  const float* w_g     = (const float*)d_in[5];
  const float* b_g     = (const float*)d_in[6];
  const float* sigma   = (const float*)d_in[7];
  float* out = (float*)d_out;

  // Workspace layout (bytes):
  //   qf     @ 0        : BN*8*2              = 524288
  //   phiT   @ 524288   : 2*NPOOL*8*2         = 131072
  //   gT     @ 655360   : 2*64*NPOOL*2        = 1048576
  //   part_m @ 1703936  : KSPLIT*BN*4         = 1048576
  //   part_l @ 2752512  : KSPLIT*BN*4         = 1048576
  //   part_o @ 3801088  : KSPLIT*2*NPIX*64*2  = 33554432   (total ~37.4 MB)
  char* ws = (char*)d_ws;
  _Float16* qf     = (_Float16*)ws;
  _Float16* phiT   = (_Float16*)(ws + 524288);
  _Float16* gT     = (_Float16*)(ws + 655360);
  float*    part_m = (float*)(ws + 1703936);
  float*    part_l = (float*)(ws + 2752512);
  _Float16* part_o = (_Float16*)(ws + 3801088);

  prep_kernel<<<256, 256, 0, stream>>>(x, w_theta, b_theta, w_phi, b_phi,
                                       w_g, b_g, qf, phiT, gT);
  attn_kernel<<<2 * 128 * KSPLIT, 256, 0, stream>>>(qf, phiT, gT,
                                                    part_m, part_l, part_o);
  reduce_kernel<<<512, 256, 0, stream>>>(part_m, part_l, part_o, x, sigma, out);
}

// Round 10
// 91.998 us; speedup vs baseline: 1.6023x; 1.6023x over previous
//
#include <hip/hip_runtime.h>
#include <hip/hip_bf16.h>

typedef _Float16 half8 __attribute__((ext_vector_type(8)));
typedef _Float16 f16x8 __attribute__((ext_vector_type(8)));
typedef __fp16 fp16x2 __attribute__((ext_vector_type(2)));
typedef float f32x16 __attribute__((ext_vector_type(16)));
typedef unsigned uint2v __attribute__((ext_vector_type(2)));

#define NPIX 16384      // H*W
#define NPOOL 4096      // pooled N
#define BN 32768        // B*N
#define KSPLIT 8
#define CHUNK 512       // NPOOL/KSPLIT
#define NSTEP 8         // CHUNK/64
#define LOG2E 1.44269504088896340736f

__device__ inline f32x16 mfma16(half8 a, half8 b, f32x16 c) {
  return __builtin_amdgcn_mfma_f32_32x32x16_f16(a, b, c, 0, 0, 0);
}

// ---- K1 (fused prep): theta f16 [BN][8]*log2e; phiT f16 [b][M][8]; gT f16 [b][64][M]
__global__ __launch_bounds__(256) void prep_kernel(
    const float* __restrict__ x,
    const float* __restrict__ w_theta, const float* __restrict__ b_theta,
    const float* __restrict__ w_phi, const float* __restrict__ b_phi,
    const float* __restrict__ w_g, const float* __restrict__ b_g,
    _Float16* __restrict__ qf, _Float16* __restrict__ phiT,
    _Float16* __restrict__ gT) {
  __shared__ float xs[64][256];
  int bid = blockIdx.x;
  int oh = bid & 1;
  int pr = (bid >> 1) & 63;
  int b  = bid >> 7;
  int t = threadIdx.x;

  const float* xb = x + (size_t)b * 64 * NPIX + pr * 256;
#pragma unroll 8
  for (int c = 0; c < 64; c++) xs[c][t] = xb[(size_t)c * NPIX + t];
  __syncthreads();

  if (oh == 0) {
    float acc[8];
#pragma unroll
    for (int j = 0; j < 8; j++) acc[j] = b_theta[j];
    for (int c = 0; c < 64; c++) {
      float xv = xs[c][t];
#pragma unroll
      for (int j = 0; j < 8; j++) acc[j] += xv * w_theta[j * 64 + c];
    }
    half8 h;
#pragma unroll
    for (int j = 0; j < 8; j++) h[j] = (_Float16)(acc[j] * LOG2E);
    *(half8*)(qf + ((size_t)b * NPIX + pr * 256 + t) * 8) = h;
  }

  int pos = t & 63;
  int ocg = t >> 6;
  int oc0 = oh * 36 + ocg * 9;
  const float* wrow[9];
  float a0[9], a1[9], a2[9], a3[9];
#pragma unroll
  for (int j = 0; j < 9; j++) {
    int oc = oc0 + j;
    float bv;
    if (oc < 64) { wrow[j] = w_g + oc * 64; bv = b_g[oc]; }
    else         { wrow[j] = w_phi + (oc - 64) * 64; bv = b_phi[oc - 64]; }
    a0[j] = bv; a1[j] = bv; a2[j] = bv; a3[j] = bv;
  }
  for (int c = 0; c < 64; c++) {
    float2 lo = *(const float2*)&xs[c][2 * pos];
    float2 hi = *(const float2*)&xs[c][128 + 2 * pos];
#pragma unroll
    for (int j = 0; j < 9; j++) {
      float wv = wrow[j][c];
      a0[j] += wv * lo.x;
      a1[j] += wv * lo.y;
      a2[j] += wv * hi.x;
      a3[j] += wv * hi.y;
    }
  }
  int m = pr * 64 + pos;
#pragma unroll
  for (int j = 0; j < 9; j++) {
    int oc = oc0 + j;
    float v = fmaxf(fmaxf(a0[j], a1[j]), fmaxf(a2[j], a3[j]));
    if (oc < 64) gT[((size_t)b * 64 + oc) * NPOOL + m] = (_Float16)v;
    else         phiT[((size_t)b * NPOOL + m) * 8 + (oc - 64)] = (_Float16)v;
  }
}

// ---- K2: per-(query, chunk) score max -> qpm[kc][BN]  (log2 units) ----
// grid = b(2) x qt(128) x kc(8) = 2048 blocks; 4 waves x 32 queries
__global__ __launch_bounds__(256, 4) void qmax_kernel(
    const _Float16* __restrict__ qf, const _Float16* __restrict__ phiT,
    float* __restrict__ qpm) {
  int bx = blockIdx.x;
  int kc = bx & (KSPLIT - 1);
  int qt = (bx >> 3) & 127;
  int b  = bx >> 10;
  int tid = threadIdx.x;
  int w = tid >> 6, lane = tid & 63;
  int q = lane & 31, hi = lane >> 5;
  int qg0 = qt * 128 + w * 32;

  half8 qfrag = {0, 0, 0, 0, 0, 0, 0, 0};
  if (!hi) qfrag = *(const half8*)(qf + ((size_t)b * NPIX + qg0 + q) * 8);
  float m = -3e38f;
  int kb0 = kc * CHUNK;
  for (int kb = kb0; kb < kb0 + CHUNK; kb += 32) {
    half8 aphi = {0, 0, 0, 0, 0, 0, 0, 0};
    if (!hi) aphi = *(const half8*)(phiT + ((size_t)b * NPOOL + kb + q) * 8);
    f32x16 sacc;
#pragma unroll
    for (int i = 0; i < 16; i++) sacc[i] = -3e38f;
    sacc = mfma16(aphi, qfrag, sacc);   // C-init -inf is absorbed: s + (-3e38) ~ still s? NO
    // NOTE: C-init must be 0 (scores are s + C). Use 0 and track max directly.
#pragma unroll
    for (int i = 0; i < 16; i++) m = fmaxf(m, sacc[i] + 3e38f);
  }
  // The above pattern is wrong arithmetically; recompute cleanly below.
  // (kept simple: redo with C=0)
  m = -3e38f;
  for (int kb = kb0; kb < kb0 + CHUNK; kb += 32) {
    half8 aphi = {0, 0, 0, 0, 0, 0, 0, 0};
    if (!hi) aphi = *(const half8*)(phiT + ((size_t)b * NPOOL + kb + q) * 8);
    f32x16 sacc;
#pragma unroll
    for (int i = 0; i < 16; i++) sacc[i] = 0.f;
    sacc = mfma16(aphi, qfrag, sacc);
    float m01 = fmaxf(fmaxf(sacc[0], sacc[1]), fmaxf(sacc[2], sacc[3]));
    float m23 = fmaxf(fmaxf(sacc[4], sacc[5]), fmaxf(sacc[6], sacc[7]));
    float m45 = fmaxf(fmaxf(sacc[8], sacc[9]), fmaxf(sacc[10], sacc[11]));
    float m67 = fmaxf(fmaxf(sacc[12], sacc[13]), fmaxf(sacc[14], sacc[15]));
    m = fmaxf(m, fmaxf(fmaxf(m01, m23), fmaxf(m45, m67)));
  }
  m = fmaxf(m, __shfl_xor(m, 32));
  if (!hi) qpm[(size_t)kc * BN + b * NPIX + qg0 + q] = m;
}

// ---- K3: flash attention partials; exact global shift; gl_lds staging ----
// grid = b(2) x qt(128) x kc(8) = 2048 blocks; 4 waves x 32 queries
__global__ __launch_bounds__(256, 4) void attn_kernel(
    const _Float16* __restrict__ qf, const _Float16* __restrict__ phiT,
    const _Float16* __restrict__ gT, const float* __restrict__ qpm,
    float* __restrict__ part_l, _Float16* __restrict__ part_o) {
  __shared__ _Float16 lds_g[2][64 * 64];   // double buffer, 8 KB each
  int bx = blockIdx.x;
  int kc = bx & (KSPLIT - 1);
  int qt = (bx >> 3) & 127;
  int b  = bx >> 10;
  int tid = threadIdx.x;
  int lane = tid & 63;
  int w = tid >> 6;
  int q = lane & 31, hi = lane >> 5;
  int qg0 = qt * 128 + w * 32;
  size_t qrow = (size_t)b * NPIX + qg0 + q;

  half8 qfrag = {0, 0, 0, 0, 0, 0, 0, 0};
  if (!hi) qfrag = *(const half8*)(qf + qrow * 8);

  // exact per-query global max = max over the 8 chunk maxes
  float mqv = qpm[qrow];
#pragma unroll
  for (int k2 = 1; k2 < KSPLIT; k2++)
    mqv = fmaxf(mqv, qpm[(size_t)k2 * BN + qrow]);
  float nm = -mqv;

  f32x16 oacc0, oacc1;
#pragma unroll
  for (int i = 0; i < 16; i++) { oacc0[i] = 0.f; oacc1[i] = 0.f; }
  float lsum = 0.f;

  int kb0 = kc * CHUNK;

  // gl_lds staging: linear LDS dest (base + lane*16), inverse-swizzled source.
  // Lane l, instr h: c = (2w+h)*8 + (l>>3), s = (l&7) ^ (l>>3)
  const _Float16* gbase0;
  const _Float16* gbase1;
  {
    int c0 = (w * 2 + 0) * 8 + (lane >> 3);
    int c1 = (w * 2 + 1) * 8 + (lane >> 3);
    int s  = (lane & 7) ^ (lane >> 3);
    gbase0 = gT + ((size_t)b * 64 + c0) * NPOOL + 8 * s;
    gbase1 = gT + ((size_t)b * 64 + c1) * NPOOL + 8 * s;
  }
#define STAGE(buf, kb)                                                        \
  do {                                                                        \
    __builtin_amdgcn_global_load_lds(                                         \
        (const __attribute__((address_space(1))) void*)(gbase0 + (kb)),       \
        (__attribute__((address_space(3))) void*)((char*)&lds_g[buf][0] +     \
                                                  (w * 2 + 0) * 1024),        \
        16, 0, 0);                                                            \
    __builtin_amdgcn_global_load_lds(                                         \
        (const __attribute__((address_space(1))) void*)(gbase1 + (kb)),       \
        (__attribute__((address_space(3))) void*)((char*)&lds_g[buf][0] +     \
                                                  (w * 2 + 1) * 1024),        \
        16, 0, 0);                                                            \
  } while (0)

  STAGE(0, kb0);
  __syncthreads();                       // buf0 visible
  int cur = 0;

#pragma unroll 1
  for (int step = 0; step < NSTEP; ++step) {
    int kb = kb0 + step * 64;
    if (step + 1 < NSTEP) STAGE(cur ^ 1, kb + 64);   // prefetch next tile
    half8 aphi0 = {0, 0, 0, 0, 0, 0, 0, 0}, aphi1 = aphi0;
    if (!hi) {
      aphi0 = *(const half8*)(phiT + ((size_t)b * NPOOL + kb + q) * 8);
      aphi1 = *(const half8*)(phiT + ((size_t)b * NPOOL + kb + 32 + q) * 8);
    }
    const _Float16* ldsb = &lds_g[cur][0];
#pragma unroll
    for (int sub = 0; sub < 2; ++sub) {
      half8 aphi = sub ? aphi1 : aphi0;
      f32x16 sacc;
#pragma unroll
      for (int i = 0; i < 16; i++) sacc[i] = nm;     // exact global shift
      sacc = mfma16(aphi, qfrag, sacc);
      float p[16];
#pragma unroll
      for (int i = 0; i < 16; i++) p[i] = exp2f(sacc[i]);   // in (0, 1]
#pragma unroll
      for (int halfk = 0; halfk < 2; ++halfk) {
        int pb = halfk * 8;
        fp16x2 h0 = __builtin_amdgcn_cvt_pkrtz(p[pb + 0], p[pb + 1]);
        fp16x2 h1 = __builtin_amdgcn_cvt_pkrtz(p[pb + 2], p[pb + 3]);
        fp16x2 h2 = __builtin_amdgcn_cvt_pkrtz(p[pb + 4], p[pb + 5]);
        fp16x2 h3 = __builtin_amdgcn_cvt_pkrtz(p[pb + 6], p[pb + 7]);
#if __has_builtin(__builtin_amdgcn_fdot2)
        const fp16x2 ones = {(__fp16)1.0f, (__fp16)1.0f};
        lsum = __builtin_amdgcn_fdot2(h0, ones, lsum, false);
        lsum = __builtin_amdgcn_fdot2(h1, ones, lsum, false);
        lsum = __builtin_amdgcn_fdot2(h2, ones, lsum, false);
        lsum = __builtin_amdgcn_fdot2(h3, ones, lsum, false);
#else
        lsum += p[pb + 0] + p[pb + 1] + p[pb + 2] + p[pb + 3];
        lsum += p[pb + 4] + p[pb + 5] + p[pb + 6] + p[pb + 7];
#endif
        unsigned A0 = __builtin_bit_cast(unsigned, h0);
        unsigned A1 = __builtin_bit_cast(unsigned, h1);
        unsigned B0 = __builtin_bit_cast(unsigned, h2);
        unsigned B1 = __builtin_bit_cast(unsigned, h3);
        union { unsigned u[4]; half8 h; } pf;
#if __has_builtin(__builtin_amdgcn_permlane32_swap)
        uint2v r0 = __builtin_amdgcn_permlane32_swap(A0, B0, false, false);
        uint2v r1 = __builtin_amdgcn_permlane32_swap(A1, B1, false, false);
        pf.u[0] = r0[0]; pf.u[1] = r1[0]; pf.u[2] = r0[1]; pf.u[3] = r1[1];
#else
        unsigned xA0 = __shfl_xor(A0, 32), xA1 = __shfl_xor(A1, 32);
        unsigned xB0 = __shfl_xor(B0, 32), xB1 = __shfl_xor(B1, 32);
        pf.u[0] = hi ? xB0 : A0;
        pf.u[1] = hi ? xB1 : A1;
        pf.u[2] = hi ? B0 : xA0;
        pf.u[3] = hi ? B1 : xA1;
#endif
        int sread = sub * 4 + halfk * 2 + hi;
#pragma unroll
        for (int ct = 0; ct < 2; ++ct) {
          int row = ct * 32 + q;
          half8 ag = *(const half8*)(ldsb + row * 64 +
                                     (((16 * sread) ^ ((row & 7) << 4)) >> 1));
          if (ct == 0) oacc0 = mfma16(ag, pf.h, oacc0);
          else         oacc1 = mfma16(ag, pf.h, oacc1);
        }
      }
    }
    if (step + 1 < NSTEP) { __syncthreads(); cur ^= 1; }  // uniform condition
  }
  lsum += __shfl_xor(lsum, 32);
  if (!hi) part_l[(size_t)kc * BN + qrow] = lsum;
  // part_o f16 layout [kc][b][n][64]; 8B packed stores
  _Float16* po = part_o + (((size_t)(kc * 2 + b) * NPIX) + qg0 + q) * 64;
#pragma unroll
  for (int ct = 0; ct < 2; ++ct) {
#pragma unroll
    for (int g = 0; g < 4; ++g) {
      float v0 = ct ? oacc1[4 * g + 0] : oacc0[4 * g + 0];
      float v1 = ct ? oacc1[4 * g + 1] : oacc0[4 * g + 1];
      float v2 = ct ? oacc1[4 * g + 2] : oacc0[4 * g + 2];
      float v3 = ct ? oacc1[4 * g + 3] : oacc0[4 * g + 3];
      uint2v u;
      u[0] = __builtin_bit_cast(unsigned, __builtin_amdgcn_cvt_pkrtz(v0, v1));
      u[1] = __builtin_bit_cast(unsigned, __builtin_amdgcn_cvt_pkrtz(v2, v3));
      *(uint2v*)(po + 32 * ct + 8 * g + 4 * hi) = u;   // ch = (r&3)+8g+4hi+32ct
    }
  }
}

// ---- K4: pure-add combine + residual epilogue ----
__global__ __launch_bounds__(256) void reduce_kernel(
    const float* __restrict__ part_l, const _Float16* __restrict__ part_o,
    const float* __restrict__ x, const float* __restrict__ sig,
    float* __restrict__ out) {
  int t = threadIdx.x;
  int cg = t >> 6;                       // 0..3 -> channels cg*16..+15
  int qi = blockIdx.x * 64 + (t & 63);
  int b = qi >> 14, n = qi & (NPIX - 1);
  float L = 0.f;
#pragma unroll
  for (int kc = 0; kc < KSPLIT; kc++) L += part_l[(size_t)kc * BN + qi];
  float o16[16];
#pragma unroll
  for (int j = 0; j < 16; j++) o16[j] = 0.f;
#pragma unroll
  for (int kc = 0; kc < KSPLIT; kc++) {
    const _Float16* po = part_o + (((size_t)(kc * 2 + b) * NPIX) + n) * 64 + cg * 16;
    f16x8 v0 = *(const f16x8*)po;
    f16x8 v1 = *(const f16x8*)(po + 8);
#pragma unroll
    for (int j = 0; j < 8; j++) {
      o16[j]     += (float)v0[j];
      o16[8 + j] += (float)v1[j];
    }
  }
  float scale = sig[0] / L;
#pragma unroll
  for (int j = 0; j < 16; j++) {
    int c = cg * 16 + j;
    size_t idx = ((size_t)b * 64 + c) * NPIX + n;
    out[idx] = x[idx] + scale * o16[j];
  }
}

extern "C" void kernel_launch(void* const* d_in, const int* in_sizes, int n_in,
                              void* d_out, int out_size, void* d_ws, size_t ws_size,
                              hipStream_t stream) {
  const float* x       = (const float*)d_in[0];
  const float* w_theta = (const float*)d_in[1];
  const float* b_theta = (const float*)d_in[2];
  const float* w_phi   = (const float*)d_in[3];
  const float* b_phi   = (const float*)d_in[4];
  const float* w_g     = (const float*)d_in[5];
  const float* b_g     = (const float*)d_in[6];
  const float* sigma   = (const float*)d_in[7];
  float* out = (float*)d_out;

  // Workspace layout (bytes):
  //   qf     @ 0        : BN*8*2              = 524288
  //   phiT   @ 524288   : 2*NPOOL*8*2         = 131072
  //   gT     @ 655360   : 2*64*NPOOL*2        = 1048576
  //   qpm    @ 1703936  : KSPLIT*BN*4         = 1048576
  //   part_l @ 2752512  : KSPLIT*BN*4         = 1048576
  //   part_o @ 3801088  : KSPLIT*2*NPIX*64*2  = 33554432   (total ~37.4 MB)
  char* ws = (char*)d_ws;
  _Float16* qf     = (_Float16*)ws;
  _Float16* phiT   = (_Float16*)(ws + 524288);
  _Float16* gT     = (_Float16*)(ws + 655360);
  float*    qpm    = (float*)(ws + 1703936);
  float*    part_l = (float*)(ws + 2752512);
  _Float16* part_o = (_Float16*)(ws + 3801088);

  prep_kernel<<<256, 256, 0, stream>>>(x, w_theta, b_theta, w_phi, b_phi,
                                       w_g, b_g, qf, phiT, gT);
  qmax_kernel<<<2 * 128 * KSPLIT, 256, 0, stream>>>(qf, phiT, qpm);
  attn_kernel<<<2 * 128 * KSPLIT, 256, 0, stream>>>(qf, phiT, gT, qpm,
                                                    part_l, part_o);
  reduce_kernel<<<512, 256, 0, stream>>>(part_l, part_o, x, sigma, out);
}

// Round 12
// 87.110 us; speedup vs baseline: 1.6922x; 1.0561x over previous
//
#include <hip/hip_runtime.h>
#include <hip/hip_bf16.h>

typedef _Float16 half8 __attribute__((ext_vector_type(8)));
typedef _Float16 f16x8 __attribute__((ext_vector_type(8)));
typedef __fp16 fp16x2 __attribute__((ext_vector_type(2)));
typedef float f32x16 __attribute__((ext_vector_type(16)));
typedef unsigned uint2v __attribute__((ext_vector_type(2)));

#define NPIX 16384      // H*W
#define NPOOL 4096      // pooled N
#define BN 32768        // B*N
#define KSPLIT 8
#define CHUNK 512       // NPOOL/KSPLIT
#define NSTEP 8         // CHUNK/64
#define LOG2E 1.44269504088896340736f

__device__ inline f32x16 mfma16(half8 a, half8 b, f32x16 c) {
  return __builtin_amdgcn_mfma_f32_32x32x16_f16(a, b, c, 0, 0, 0);
}

// ---- K1 (fused prep): theta f16 [BN][8]*log2e; phiT f16 [b][M][8]; gT f16 [b][64][M]
__global__ __launch_bounds__(256) void prep_kernel(
    const float* __restrict__ x,
    const float* __restrict__ w_theta, const float* __restrict__ b_theta,
    const float* __restrict__ w_phi, const float* __restrict__ b_phi,
    const float* __restrict__ w_g, const float* __restrict__ b_g,
    _Float16* __restrict__ qf, _Float16* __restrict__ phiT,
    _Float16* __restrict__ gT) {
  __shared__ float xs[64][256];
  int bid = blockIdx.x;
  int oh = bid & 1;
  int pr = (bid >> 1) & 63;
  int b  = bid >> 7;
  int t = threadIdx.x;

  const float* xb = x + (size_t)b * 64 * NPIX + pr * 256;
#pragma unroll 8
  for (int c = 0; c < 64; c++) xs[c][t] = xb[(size_t)c * NPIX + t];
  __syncthreads();

  if (oh == 0) {
    float acc[8];
#pragma unroll
    for (int j = 0; j < 8; j++) acc[j] = b_theta[j];
    for (int c = 0; c < 64; c++) {
      float xv = xs[c][t];
#pragma unroll
      for (int j = 0; j < 8; j++) acc[j] += xv * w_theta[j * 64 + c];
    }
    half8 h;
#pragma unroll
    for (int j = 0; j < 8; j++) h[j] = (_Float16)(acc[j] * LOG2E);
    *(half8*)(qf + ((size_t)b * NPIX + pr * 256 + t) * 8) = h;
  }

  int pos = t & 63;
  int ocg = t >> 6;
  int oc0 = oh * 36 + ocg * 9;
  const float* wrow[9];
  float a0[9], a1[9], a2[9], a3[9];
#pragma unroll
  for (int j = 0; j < 9; j++) {
    int oc = oc0 + j;
    float bv;
    if (oc < 64) { wrow[j] = w_g + oc * 64; bv = b_g[oc]; }
    else         { wrow[j] = w_phi + (oc - 64) * 64; bv = b_phi[oc - 64]; }
    a0[j] = bv; a1[j] = bv; a2[j] = bv; a3[j] = bv;
  }
  for (int c = 0; c < 64; c++) {
    float2 lo = *(const float2*)&xs[c][2 * pos];
    float2 hi = *(const float2*)&xs[c][128 + 2 * pos];
#pragma unroll
    for (int j = 0; j < 9; j++) {
      float wv = wrow[j][c];
      a0[j] += wv * lo.x;
      a1[j] += wv * lo.y;
      a2[j] += wv * hi.x;
      a3[j] += wv * hi.y;
    }
  }
  int m = pr * 64 + pos;
#pragma unroll
  for (int j = 0; j < 9; j++) {
    int oc = oc0 + j;
    float v = fmaxf(fmaxf(a0[j], a1[j]), fmaxf(a2[j], a3[j]));
    if (oc < 64) gT[((size_t)b * 64 + oc) * NPOOL + m] = (_Float16)v;
    else         phiT[((size_t)b * NPOOL + m) * 8 + (oc - 64)] = (_Float16)v;
  }
}

// ---- K2: flash attention partials; fused exact chunk-max; gl_lds staging ----
// grid = b(2) x qt(128) x kc(8) = 2048 blocks; 4 waves x 32 queries
__global__ __launch_bounds__(256, 4) void attn_kernel(
    const _Float16* __restrict__ qf, const _Float16* __restrict__ phiT,
    const _Float16* __restrict__ gT,
    float* __restrict__ part_m, float* __restrict__ part_l,
    _Float16* __restrict__ part_o) {
  __shared__ _Float16 lds_g[2][64 * 64];   // double buffer, 8 KB each
  int bx = blockIdx.x;
  int kc = bx & (KSPLIT - 1);
  int qt = (bx >> 3) & 127;
  int b  = bx >> 10;
  int tid = threadIdx.x;
  int lane = tid & 63;
  int w = tid >> 6;
  int q = lane & 31, hi = lane >> 5;
  int qg0 = qt * 128 + w * 32;
  size_t qrow = (size_t)b * NPIX + qg0 + q;

  half8 qfrag = {0, 0, 0, 0, 0, 0, 0, 0};
  if (!hi) qfrag = *(const half8*)(qf + qrow * 8);

  int kb0 = kc * CHUNK;

  // ---- pre-pass: exact chunk max (scores only; phiT is L2-resident) ----
  float mchunk = -3e38f;
#pragma unroll 4
  for (int kb = kb0; kb < kb0 + CHUNK; kb += 32) {
    half8 aphi = {0, 0, 0, 0, 0, 0, 0, 0};
    if (!hi) aphi = *(const half8*)(phiT + ((size_t)b * NPOOL + kb + q) * 8);
    f32x16 sacc;
#pragma unroll
    for (int i = 0; i < 16; i++) sacc[i] = 0.f;
    sacc = mfma16(aphi, qfrag, sacc);
    float m01 = fmaxf(fmaxf(sacc[0], sacc[1]), fmaxf(sacc[2], sacc[3]));
    float m23 = fmaxf(fmaxf(sacc[4], sacc[5]), fmaxf(sacc[6], sacc[7]));
    float m45 = fmaxf(fmaxf(sacc[8], sacc[9]), fmaxf(sacc[10], sacc[11]));
    float m67 = fmaxf(fmaxf(sacc[12], sacc[13]), fmaxf(sacc[14], sacc[15]));
    mchunk = fmaxf(mchunk, fmaxf(fmaxf(m01, m23), fmaxf(m45, m67)));
  }
  mchunk = fmaxf(mchunk, __shfl_xor(mchunk, 32));   // pair-shared exact max
  float nm = -mchunk;

  f32x16 oacc0, oacc1;
#pragma unroll
  for (int i = 0; i < 16; i++) { oacc0[i] = 0.f; oacc1[i] = 0.f; }
  float lsum = 0.f;

  // gl_lds staging: linear LDS dest (base + lane*16), inverse-swizzled source.
  const _Float16* gbase0;
  const _Float16* gbase1;
  {
    int c0 = (w * 2 + 0) * 8 + (lane >> 3);
    int c1 = (w * 2 + 1) * 8 + (lane >> 3);
    int s  = (lane & 7) ^ (lane >> 3);
    gbase0 = gT + ((size_t)b * 64 + c0) * NPOOL + 8 * s;
    gbase1 = gT + ((size_t)b * 64 + c1) * NPOOL + 8 * s;
  }
#define STAGE(buf, kb)                                                        \
  do {                                                                        \
    __builtin_amdgcn_global_load_lds(                                         \
        (const __attribute__((address_space(1))) void*)(gbase0 + (kb)),       \
        (__attribute__((address_space(3))) void*)((char*)&lds_g[buf][0] +     \
                                                  (w * 2 + 0) * 1024),        \
        16, 0, 0);                                                            \
    __builtin_amdgcn_global_load_lds(                                         \
        (const __attribute__((address_space(1))) void*)(gbase1 + (kb)),       \
        (__attribute__((address_space(3))) void*)((char*)&lds_g[buf][0] +     \
                                                  (w * 2 + 1) * 1024),        \
        16, 0, 0);                                                            \
  } while (0)

  STAGE(0, kb0);
  __syncthreads();                       // buf0 visible
  int cur = 0;

#pragma unroll 1
  for (int step = 0; step < NSTEP; ++step) {
    int kb = kb0 + step * 64;
    if (step + 1 < NSTEP) STAGE(cur ^ 1, kb + 64);   // prefetch next tile
    half8 aphi0 = {0, 0, 0, 0, 0, 0, 0, 0}, aphi1 = aphi0;
    if (!hi) {
      aphi0 = *(const half8*)(phiT + ((size_t)b * NPOOL + kb + q) * 8);
      aphi1 = *(const half8*)(phiT + ((size_t)b * NPOOL + kb + 32 + q) * 8);
    }
    const _Float16* ldsb = &lds_g[cur][0];
#pragma unroll
    for (int sub = 0; sub < 2; ++sub) {
      half8 aphi = sub ? aphi1 : aphi0;
      f32x16 sacc;
#pragma unroll
      for (int i = 0; i < 16; i++) sacc[i] = nm;     // exact chunk shift
      sacc = mfma16(aphi, qfrag, sacc);
      float p[16];
#pragma unroll
      for (int i = 0; i < 16; i++) p[i] = exp2f(sacc[i]);   // in (0, 1]
#pragma unroll
      for (int halfk = 0; halfk < 2; ++halfk) {
        int pb = halfk * 8;
        fp16x2 h0 = __builtin_amdgcn_cvt_pkrtz(p[pb + 0], p[pb + 1]);
        fp16x2 h1 = __builtin_amdgcn_cvt_pkrtz(p[pb + 2], p[pb + 3]);
        fp16x2 h2 = __builtin_amdgcn_cvt_pkrtz(p[pb + 4], p[pb + 5]);
        fp16x2 h3 = __builtin_amdgcn_cvt_pkrtz(p[pb + 6], p[pb + 7]);
#if __has_builtin(__builtin_amdgcn_fdot2)
        const fp16x2 ones = {(__fp16)1.0f, (__fp16)1.0f};
        lsum = __builtin_amdgcn_fdot2(h0, ones, lsum, false);
        lsum = __builtin_amdgcn_fdot2(h1, ones, lsum, false);
        lsum = __builtin_amdgcn_fdot2(h2, ones, lsum, false);
        lsum = __builtin_amdgcn_fdot2(h3, ones, lsum, false);
#else
        lsum += p[pb + 0] + p[pb + 1] + p[pb + 2] + p[pb + 3];
        lsum += p[pb + 4] + p[pb + 5] + p[pb + 6] + p[pb + 7];
#endif
        unsigned A0 = __builtin_bit_cast(unsigned, h0);
        unsigned A1 = __builtin_bit_cast(unsigned, h1);
        unsigned B0 = __builtin_bit_cast(unsigned, h2);
        unsigned B1 = __builtin_bit_cast(unsigned, h3);
        union { unsigned u[4]; half8 h; } pf;
#if __has_builtin(__builtin_amdgcn_permlane32_swap)
        uint2v r0 = __builtin_amdgcn_permlane32_swap(A0, B0, false, false);
        uint2v r1 = __builtin_amdgcn_permlane32_swap(A1, B1, false, false);
        pf.u[0] = r0[0]; pf.u[1] = r1[0]; pf.u[2] = r0[1]; pf.u[3] = r1[1];
#else
        unsigned xA0 = __shfl_xor(A0, 32), xA1 = __shfl_xor(A1, 32);
        unsigned xB0 = __shfl_xor(B0, 32), xB1 = __shfl_xor(B1, 32);
        pf.u[0] = hi ? xB0 : A0;
        pf.u[1] = hi ? xB1 : A1;
        pf.u[2] = hi ? B0 : xA0;
        pf.u[3] = hi ? B1 : xA1;
#endif
        int sread = sub * 4 + halfk * 2 + hi;
        __builtin_amdgcn_s_setprio(1);
#pragma unroll
        for (int ct = 0; ct < 2; ++ct) {
          int row = ct * 32 + q;
          half8 ag = *(const half8*)(ldsb + row * 64 +
                                     (((16 * sread) ^ ((row & 7) << 4)) >> 1));
          if (ct == 0) oacc0 = mfma16(ag, pf.h, oacc0);
          else         oacc1 = mfma16(ag, pf.h, oacc1);
        }
        __builtin_amdgcn_s_setprio(0);
      }
    }
    if (step + 1 < NSTEP) { __syncthreads(); cur ^= 1; }  // uniform condition
  }
  lsum += __shfl_xor(lsum, 32);
  if (!hi) {
    part_m[(size_t)kc * BN + qrow] = mchunk;
    part_l[(size_t)kc * BN + qrow] = lsum;
  }
  // part_o f16 layout [kc][b][n][64]; 8B packed stores
  _Float16* po = part_o + (((size_t)(kc * 2 + b) * NPIX) + qg0 + q) * 64;
#pragma unroll
  for (int ct = 0; ct < 2; ++ct) {
#pragma unroll
    for (int g = 0; g < 4; ++g) {
      float v0 = ct ? oacc1[4 * g + 0] : oacc0[4 * g + 0];
      float v1 = ct ? oacc1[4 * g + 1] : oacc0[4 * g + 1];
      float v2 = ct ? oacc1[4 * g + 2] : oacc0[4 * g + 2];
      float v3 = ct ? oacc1[4 * g + 3] : oacc0[4 * g + 3];
      uint2v u;
      u[0] = __builtin_bit_cast(unsigned, __builtin_amdgcn_cvt_pkrtz(v0, v1));
      u[1] = __builtin_bit_cast(unsigned, __builtin_amdgcn_cvt_pkrtz(v2, v3));
      *(uint2v*)(po + 32 * ct + 8 * g + 4 * hi) = u;   // ch = (r&3)+8g+4hi+32ct
    }
  }
}

// ---- K3: max-weighted combine + residual epilogue ----
__global__ __launch_bounds__(256) void reduce_kernel(
    const float* __restrict__ part_m, const float* __restrict__ part_l,
    const _Float16* __restrict__ part_o, const float* __restrict__ x,
    const float* __restrict__ sig, float* __restrict__ out) {
  int t = threadIdx.x;
  int cg = t >> 6;                       // 0..3 -> channels cg*16..+15
  int qi = blockIdx.x * 64 + (t & 63);
  int b = qi >> 14, n = qi & (NPIX - 1);
  float mv[KSPLIT], lv[KSPLIT];
  float mstar = -3e38f;
#pragma unroll
  for (int kc = 0; kc < KSPLIT; kc++) {
    mv[kc] = part_m[(size_t)kc * BN + qi];
    lv[kc] = part_l[(size_t)kc * BN + qi];
    mstar = fmaxf(mstar, mv[kc]);
  }
  float wk[KSPLIT], L = 0.f;
#pragma unroll
  for (int kc = 0; kc < KSPLIT; kc++) {
    wk[kc] = exp2f(mv[kc] - mstar);
    L += lv[kc] * wk[kc];
  }
  float o16[16];
#pragma unroll
  for (int j = 0; j < 16; j++) o16[j] = 0.f;
#pragma unroll
  for (int kc = 0; kc < KSPLIT; kc++) {
    const _Float16* po = part_o + (((size_t)(kc * 2 + b) * NPIX) + n) * 64 + cg * 16;
    f16x8 v0 = *(const f16x8*)po;
    f16x8 v1 = *(const f16x8*)(po + 8);
    float wv = wk[kc];
#pragma unroll
    for (int j = 0; j < 8; j++) {
      o16[j]     += wv * (float)v0[j];
      o16[8 + j] += wv * (float)v1[j];
    }
  }
  float scale = sig[0] / L;
#pragma unroll
  for (int j = 0; j < 16; j++) {
    int c = cg * 16 + j;
    size_t idx = ((size_t)b * 64 + c) * NPIX + n;
    out[idx] = x[idx] + scale * o16[j];
  }
}

extern "C" void kernel_launch(void* const* d_in, const int* in_sizes, int n_in,
                              void* d_out, int out_size, void* d_ws, size_t ws_size,
                              hipStream_t stream) {
  const float* x       = (const float*)d_in[0];
  const float* w_theta = (const float*)d_in[1];
  const float* b_theta = (const float*)d_in[2];
  const float* w_phi   = (const float*)d_in[3];
  const float* b_phi   = (const float*)d_in[4];
  const float* w_g     = (const float*)d_in[5];
  const float* b_g     = (const float*)d_in[6];
  const float* sigma   = (const float*)d_in[7];
  float* out = (float*)d_out;

  // Workspace layout (bytes):
  //   qf     @ 0        : BN*8*2              = 524288
  //   phiT   @ 524288   : 2*NPOOL*8*2         = 131072
  //   gT     @ 655360   : 2*64*NPOOL*2        = 1048576
  //   part_m @ 1703936  : KSPLIT*BN*4         = 1048576
  //   part_l @ 2752512  : KSPLIT*BN*4         = 1048576
  //   part_o @ 3801088  : KSPLIT*2*NPIX*64*2  = 33554432   (total ~37.4 MB)
  char* ws = (char*)d_ws;
  _Float16* qf     = (_Float16*)ws;
  _Float16* phiT   = (_Float16*)(ws + 524288);
  _Float16* gT     = (_Float16*)(ws + 655360);
  float*    part_m = (float*)(ws + 1703936);
  float*    part_l = (float*)(ws + 2752512);
  _Float16* part_o = (_Float16*)(ws + 3801088);

  prep_kernel<<<256, 256, 0, stream>>>(x, w_theta, b_theta, w_phi, b_phi,
                                       w_g, b_g, qf, phiT, gT);
  attn_kernel<<<2 * 128 * KSPLIT, 256, 0, stream>>>(qf, phiT, gT,
                                                    part_m, part_l, part_o);
  reduce_kernel<<<512, 256, 0, stream>>>(part_m, part_l, part_o, x, sigma, out);
}

// Round 13
// 83.750 us; speedup vs baseline: 1.7601x; 1.0401x over previous
//
#include <hip/hip_runtime.h>
#include <hip/hip_bf16.h>

typedef _Float16 half8 __attribute__((ext_vector_type(8)));
typedef _Float16 f16x8 __attribute__((ext_vector_type(8)));
typedef __fp16 fp16x2 __attribute__((ext_vector_type(2)));
typedef __bf16 bf16x2v __attribute__((ext_vector_type(2)));
typedef __bf16 bf16x8 __attribute__((ext_vector_type(8)));
typedef float f32x16 __attribute__((ext_vector_type(16)));
typedef unsigned uint2v __attribute__((ext_vector_type(2)));

#define NPIX 16384      // H*W
#define NPOOL 4096      // pooled N
#define BN 32768        // B*N
#define KSPLIT 8
#define CHUNK 512       // NPOOL/KSPLIT
#define NSTEP 8         // CHUNK/64
#define LOG2E 1.44269504088896340736f

__device__ inline f32x16 mfma16(half8 a, half8 b, f32x16 c) {
  return __builtin_amdgcn_mfma_f32_32x32x16_f16(a, b, c, 0, 0, 0);
}
__device__ inline f32x16 mfma16b(bf16x8 a, bf16x8 b, f32x16 c) {
  return __builtin_amdgcn_mfma_f32_32x32x16_bf16(a, b, c, 0, 0, 0);
}

// ---- K1 (fused prep): theta f16 [BN][8]*log2e; phiT f16 [b][M][8]; gT bf16 [b][64][M]
__global__ __launch_bounds__(256) void prep_kernel(
    const float* __restrict__ x,
    const float* __restrict__ w_theta, const float* __restrict__ b_theta,
    const float* __restrict__ w_phi, const float* __restrict__ b_phi,
    const float* __restrict__ w_g, const float* __restrict__ b_g,
    _Float16* __restrict__ qf, _Float16* __restrict__ phiT,
    __bf16* __restrict__ gT) {
  __shared__ float xs[64][256];
  int bid = blockIdx.x;
  int oh = bid & 1;
  int pr = (bid >> 1) & 63;
  int b  = bid >> 7;
  int t = threadIdx.x;

  const float* xb = x + (size_t)b * 64 * NPIX + pr * 256;
#pragma unroll 8
  for (int c = 0; c < 64; c++) xs[c][t] = xb[(size_t)c * NPIX + t];
  __syncthreads();

  if (oh == 0) {
    float acc[8];
#pragma unroll
    for (int j = 0; j < 8; j++) acc[j] = b_theta[j];
    for (int c = 0; c < 64; c++) {
      float xv = xs[c][t];
#pragma unroll
      for (int j = 0; j < 8; j++) acc[j] += xv * w_theta[j * 64 + c];
    }
    half8 h;
#pragma unroll
    for (int j = 0; j < 8; j++) h[j] = (_Float16)(acc[j] * LOG2E);
    *(half8*)(qf + ((size_t)b * NPIX + pr * 256 + t) * 8) = h;
  }

  int pos = t & 63;
  int ocg = t >> 6;
  int oc0 = oh * 36 + ocg * 9;
  const float* wrow[9];
  float a0[9], a1[9], a2[9], a3[9];
#pragma unroll
  for (int j = 0; j < 9; j++) {
    int oc = oc0 + j;
    float bv;
    if (oc < 64) { wrow[j] = w_g + oc * 64; bv = b_g[oc]; }
    else         { wrow[j] = w_phi + (oc - 64) * 64; bv = b_phi[oc - 64]; }
    a0[j] = bv; a1[j] = bv; a2[j] = bv; a3[j] = bv;
  }
  for (int c = 0; c < 64; c++) {
    float2 lo = *(const float2*)&xs[c][2 * pos];
    float2 hi = *(const float2*)&xs[c][128 + 2 * pos];
#pragma unroll
    for (int j = 0; j < 9; j++) {
      float wv = wrow[j][c];
      a0[j] += wv * lo.x;
      a1[j] += wv * lo.y;
      a2[j] += wv * hi.x;
      a3[j] += wv * hi.y;
    }
  }
  int m = pr * 64 + pos;
#pragma unroll
  for (int j = 0; j < 9; j++) {
    int oc = oc0 + j;
    float v = fmaxf(fmaxf(a0[j], a1[j]), fmaxf(a2[j], a3[j]));
    if (oc < 64) gT[((size_t)b * 64 + oc) * NPOOL + m] = (__bf16)v;
    else         phiT[((size_t)b * NPOOL + m) * 8 + (oc - 64)] = (_Float16)v;
  }
}

// ---- K2: flash attention partials; shift-free bf16-P softmax; gl_lds staging ----
// grid = b(2) x qt(128) x kc(8) = 2048 blocks; 4 waves x 32 queries
__global__ __launch_bounds__(256, 4) void attn_kernel(
    const _Float16* __restrict__ qf, const _Float16* __restrict__ phiT,
    const __bf16* __restrict__ gT,
    float* __restrict__ part_l, _Float16* __restrict__ part_o) {
  __shared__ __bf16 lds_g[2][64 * 64];   // double buffer, 8 KB each
  int bx = blockIdx.x;
  int kc = bx & (KSPLIT - 1);
  int qt = (bx >> 3) & 127;
  int b  = bx >> 10;
  int tid = threadIdx.x;
  int lane = tid & 63;
  int w = tid >> 6;
  int q = lane & 31, hi = lane >> 5;
  int qg0 = qt * 128 + w * 32;
  size_t qrow = (size_t)b * NPIX + qg0 + q;

  half8 qfrag = {0, 0, 0, 0, 0, 0, 0, 0};
  if (!hi) qfrag = *(const half8*)(qf + qrow * 8);

  f32x16 oacc0, oacc1;
#pragma unroll
  for (int i = 0; i < 16; i++) { oacc0[i] = 0.f; oacc1[i] = 0.f; }
  float lsum = 0.f;

  int kb0 = kc * CHUNK;

  // gl_lds staging: linear LDS dest (base + lane*16), inverse-swizzled source.
  const __bf16* gbase0;
  const __bf16* gbase1;
  {
    int c0 = (w * 2 + 0) * 8 + (lane >> 3);
    int c1 = (w * 2 + 1) * 8 + (lane >> 3);
    int s  = (lane & 7) ^ (lane >> 3);
    gbase0 = gT + ((size_t)b * 64 + c0) * NPOOL + 8 * s;
    gbase1 = gT + ((size_t)b * 64 + c1) * NPOOL + 8 * s;
  }
#define STAGE(buf, kb)                                                        \
  do {                                                                        \
    __builtin_amdgcn_global_load_lds(                                         \
        (const __attribute__((address_space(1))) void*)(gbase0 + (kb)),       \
        (__attribute__((address_space(3))) void*)((char*)&lds_g[buf][0] +     \
                                                  (w * 2 + 0) * 1024),        \
        16, 0, 0);                                                            \
    __builtin_amdgcn_global_load_lds(                                         \
        (const __attribute__((address_space(1))) void*)(gbase1 + (kb)),       \
        (__attribute__((address_space(3))) void*)((char*)&lds_g[buf][0] +     \
                                                  (w * 2 + 1) * 1024),        \
        16, 0, 0);                                                            \
  } while (0)

  STAGE(0, kb0);
  __syncthreads();                       // buf0 visible
  int cur = 0;

#pragma unroll 1
  for (int step = 0; step < NSTEP; ++step) {
    int kb = kb0 + step * 64;
    if (step + 1 < NSTEP) STAGE(cur ^ 1, kb + 64);   // prefetch next tile
    half8 aphi0 = {0, 0, 0, 0, 0, 0, 0, 0}, aphi1 = aphi0;
    if (!hi) {
      aphi0 = *(const half8*)(phiT + ((size_t)b * NPOOL + kb + q) * 8);
      aphi1 = *(const half8*)(phiT + ((size_t)b * NPOOL + kb + 32 + q) * 8);
    }
    const __bf16* ldsb = &lds_g[cur][0];
#pragma unroll
    for (int sub = 0; sub < 2; ++sub) {
      half8 aphi = sub ? aphi1 : aphi0;
      f32x16 sacc;
#pragma unroll
      for (int i = 0; i < 16; i++) sacc[i] = 0.f;    // no shift needed (bf16 P)
      sacc = mfma16(aphi, qfrag, sacc);
      float p[16];
#pragma unroll
      for (int i = 0; i < 16; i++) p[i] = exp2f(fminf(sacc[i], 80.f));
      lsum += (((p[0] + p[1]) + (p[2] + p[3])) + ((p[4] + p[5]) + (p[6] + p[7]))) +
              (((p[8] + p[9]) + (p[10] + p[11])) + ((p[12] + p[13]) + (p[14] + p[15])));
#pragma unroll
      for (int halfk = 0; halfk < 2; ++halfk) {
        int pb = halfk * 8;
        bf16x2v t0 = {(__bf16)p[pb + 0], (__bf16)p[pb + 1]};
        bf16x2v t1 = {(__bf16)p[pb + 2], (__bf16)p[pb + 3]};
        bf16x2v t2 = {(__bf16)p[pb + 4], (__bf16)p[pb + 5]};
        bf16x2v t3 = {(__bf16)p[pb + 6], (__bf16)p[pb + 7]};
        unsigned A0 = __builtin_bit_cast(unsigned, t0);
        unsigned A1 = __builtin_bit_cast(unsigned, t1);
        unsigned B0 = __builtin_bit_cast(unsigned, t2);
        unsigned B1 = __builtin_bit_cast(unsigned, t3);
        union { unsigned u[4]; bf16x8 h; } pf;
#if __has_builtin(__builtin_amdgcn_permlane32_swap)
        uint2v r0 = __builtin_amdgcn_permlane32_swap(A0, B0, false, false);
        uint2v r1 = __builtin_amdgcn_permlane32_swap(A1, B1, false, false);
        pf.u[0] = r0[0]; pf.u[1] = r1[0]; pf.u[2] = r0[1]; pf.u[3] = r1[1];
#else
        unsigned xA0 = __shfl_xor(A0, 32), xA1 = __shfl_xor(A1, 32);
        unsigned xB0 = __shfl_xor(B0, 32), xB1 = __shfl_xor(B1, 32);
        pf.u[0] = hi ? xB0 : A0;
        pf.u[1] = hi ? xB1 : A1;
        pf.u[2] = hi ? B0 : xA0;
        pf.u[3] = hi ? B1 : xA1;
#endif
        int sread = sub * 4 + halfk * 2 + hi;
        __builtin_amdgcn_s_setprio(1);
#pragma unroll
        for (int ct = 0; ct < 2; ++ct) {
          int row = ct * 32 + q;
          bf16x8 ag = *(const bf16x8*)(ldsb + row * 64 +
                                       (((16 * sread) ^ ((row & 7) << 4)) >> 1));
          if (ct == 0) oacc0 = mfma16b(ag, pf.h, oacc0);
          else         oacc1 = mfma16b(ag, pf.h, oacc1);
        }
        __builtin_amdgcn_s_setprio(0);
      }
    }
    if (step + 1 < NSTEP) { __syncthreads(); cur ^= 1; }  // uniform condition
  }
  lsum += __shfl_xor(lsum, 32);          // chunk-total l (both half-lanes)
  float rl = 1.0f / lsum;
  if (!hi) part_l[(size_t)kc * BN + qrow] = lsum;
  // part_o f16 layout [kc][b][n][64] holds NORMALIZED o/l; 8B packed stores
  _Float16* po = part_o + (((size_t)(kc * 2 + b) * NPIX) + qg0 + q) * 64;
#pragma unroll
  for (int ct = 0; ct < 2; ++ct) {
#pragma unroll
    for (int g = 0; g < 4; ++g) {
      float v0 = (ct ? oacc1[4 * g + 0] : oacc0[4 * g + 0]) * rl;
      float v1 = (ct ? oacc1[4 * g + 1] : oacc0[4 * g + 1]) * rl;
      float v2 = (ct ? oacc1[4 * g + 2] : oacc0[4 * g + 2]) * rl;
      float v3 = (ct ? oacc1[4 * g + 3] : oacc0[4 * g + 3]) * rl;
      uint2v u;
      u[0] = __builtin_bit_cast(unsigned, __builtin_amdgcn_cvt_pkrtz(v0, v1));
      u[1] = __builtin_bit_cast(unsigned, __builtin_amdgcn_cvt_pkrtz(v2, v3));
      *(uint2v*)(po + 32 * ct + 8 * g + 4 * hi) = u;   // ch = (r&3)+8g+4hi+32ct
    }
  }
}

// ---- K3: l-weighted combine + residual epilogue ----
__global__ __launch_bounds__(256) void reduce_kernel(
    const float* __restrict__ part_l, const _Float16* __restrict__ part_o,
    const float* __restrict__ x, const float* __restrict__ sig,
    float* __restrict__ out) {
  int t = threadIdx.x;
  int cg = t >> 6;                       // 0..3 -> channels cg*16..+15
  int qi = blockIdx.x * 64 + (t & 63);
  int b = qi >> 14, n = qi & (NPIX - 1);
  float lv[KSPLIT], L = 0.f;
#pragma unroll
  for (int kc = 0; kc < KSPLIT; kc++) {
    lv[kc] = part_l[(size_t)kc * BN + qi];
    L += lv[kc];
  }
  float o16[16];
#pragma unroll
  for (int j = 0; j < 16; j++) o16[j] = 0.f;
#pragma unroll
  for (int kc = 0; kc < KSPLIT; kc++) {
    const _Float16* po = part_o + (((size_t)(kc * 2 + b) * NPIX) + n) * 64 + cg * 16;
    f16x8 v0 = *(const f16x8*)po;
    f16x8 v1 = *(const f16x8*)(po + 8);
    float wv = lv[kc];
#pragma unroll
    for (int j = 0; j < 8; j++) {
      o16[j]     += wv * (float)v0[j];
      o16[8 + j] += wv * (float)v1[j];
    }
  }
  float scale = sig[0] / L;
#pragma unroll
  for (int j = 0; j < 16; j++) {
    int c = cg * 16 + j;
    size_t idx = ((size_t)b * 64 + c) * NPIX + n;
    out[idx] = x[idx] + scale * o16[j];
  }
}

extern "C" void kernel_launch(void* const* d_in, const int* in_sizes, int n_in,
                              void* d_out, int out_size, void* d_ws, size_t ws_size,
                              hipStream_t stream) {
  const float* x       = (const float*)d_in[0];
  const float* w_theta = (const float*)d_in[1];
  const float* b_theta = (const float*)d_in[2];
  const float* w_phi   = (const float*)d_in[3];
  const float* b_phi   = (const float*)d_in[4];
  const float* w_g     = (const float*)d_in[5];
  const float* b_g     = (const float*)d_in[6];
  const float* sigma   = (const float*)d_in[7];
  float* out = (float*)d_out;

  // Workspace layout (bytes):
  //   qf     @ 0        : BN*8*2              = 524288
  //   phiT   @ 524288   : 2*NPOOL*8*2         = 131072
  //   gT     @ 655360   : 2*64*NPOOL*2        = 1048576  (bf16)
  //   part_l @ 1703936  : KSPLIT*BN*4         = 1048576
  //   part_o @ 2752512  : KSPLIT*2*NPIX*64*2  = 33554432   (total ~36.3 MB)
  char* ws = (char*)d_ws;
  _Float16* qf     = (_Float16*)ws;
  _Float16* phiT   = (_Float16*)(ws + 524288);
  __bf16*   gT     = (__bf16*)(ws + 655360);
  float*    part_l = (float*)(ws + 1703936);
  _Float16* part_o = (_Float16*)(ws + 2752512);

  prep_kernel<<<256, 256, 0, stream>>>(x, w_theta, b_theta, w_phi, b_phi,
                                       w_g, b_g, qf, phiT, gT);
  attn_kernel<<<2 * 128 * KSPLIT, 256, 0, stream>>>(qf, phiT, gT,
                                                    part_l, part_o);
  reduce_kernel<<<512, 256, 0, stream>>>(part_l, part_o, x, sigma, out);
}

// Round 14
// 67.376 us; speedup vs baseline: 2.1878x; 1.2430x over previous
//
#include <hip/hip_runtime.h>
#include <hip/hip_bf16.h>

typedef _Float16 half8 __attribute__((ext_vector_type(8)));
typedef _Float16 f16x8 __attribute__((ext_vector_type(8)));
typedef __fp16 fp16x2 __attribute__((ext_vector_type(2)));
typedef __bf16 bf16x2v __attribute__((ext_vector_type(2)));
typedef __bf16 bf16x8 __attribute__((ext_vector_type(8)));
typedef float f32x16 __attribute__((ext_vector_type(16)));
typedef unsigned uint2v __attribute__((ext_vector_type(2)));

#define NPIX 16384      // H*W
#define NPOOL 4096      // pooled N
#define BN 32768        // B*N
#define KSPLIT 4
#define CHUNK 1024      // NPOOL/KSPLIT
#define NSTEP 16        // CHUNK/64
#define LOG2E 1.44269504088896340736f

__device__ inline f32x16 mfma16(half8 a, half8 b, f32x16 c) {
  return __builtin_amdgcn_mfma_f32_32x32x16_f16(a, b, c, 0, 0, 0);
}
__device__ inline f32x16 mfma16b(bf16x8 a, bf16x8 b, f32x16 c) {
  return __builtin_amdgcn_mfma_f32_32x32x16_bf16(a, b, c, 0, 0, 0);
}
__device__ inline float fast_exp2(float x) {
#if __has_builtin(__builtin_amdgcn_exp2f)
  return __builtin_amdgcn_exp2f(x);      // raw v_exp_f32 (1 inst, <=1 ulp)
#else
  return exp2f(x);
#endif
}

// ---- K1 (fused prep): theta f16 [BN][8]*log2e; phiT f16 [b][M][8]; gT bf16 [b][64][M]
__global__ __launch_bounds__(256) void prep_kernel(
    const float* __restrict__ x,
    const float* __restrict__ w_theta, const float* __restrict__ b_theta,
    const float* __restrict__ w_phi, const float* __restrict__ b_phi,
    const float* __restrict__ w_g, const float* __restrict__ b_g,
    _Float16* __restrict__ qf, _Float16* __restrict__ phiT,
    __bf16* __restrict__ gT) {
  __shared__ float xs[64][256];
  int bid = blockIdx.x;
  int oh = bid & 1;
  int pr = (bid >> 1) & 63;
  int b  = bid >> 7;
  int t = threadIdx.x;

  const float* xb = x + (size_t)b * 64 * NPIX + pr * 256;
#pragma unroll 8
  for (int c = 0; c < 64; c++) xs[c][t] = xb[(size_t)c * NPIX + t];
  __syncthreads();

  if (oh == 0) {
    float acc[8];
#pragma unroll
    for (int j = 0; j < 8; j++) acc[j] = b_theta[j];
    for (int c = 0; c < 64; c++) {
      float xv = xs[c][t];
#pragma unroll
      for (int j = 0; j < 8; j++) acc[j] += xv * w_theta[j * 64 + c];
    }
    half8 h;
#pragma unroll
    for (int j = 0; j < 8; j++) h[j] = (_Float16)(acc[j] * LOG2E);
    *(half8*)(qf + ((size_t)b * NPIX + pr * 256 + t) * 8) = h;
  }

  int pos = t & 63;
  int ocg = t >> 6;
  int oc0 = oh * 36 + ocg * 9;
  const float* wrow[9];
  float a0[9], a1[9], a2[9], a3[9];
#pragma unroll
  for (int j = 0; j < 9; j++) {
    int oc = oc0 + j;
    float bv;
    if (oc < 64) { wrow[j] = w_g + oc * 64; bv = b_g[oc]; }
    else         { wrow[j] = w_phi + (oc - 64) * 64; bv = b_phi[oc - 64]; }
    a0[j] = bv; a1[j] = bv; a2[j] = bv; a3[j] = bv;
  }
  for (int c = 0; c < 64; c++) {
    float2 lo = *(const float2*)&xs[c][2 * pos];
    float2 hi = *(const float2*)&xs[c][128 + 2 * pos];
#pragma unroll
    for (int j = 0; j < 9; j++) {
      float wv = wrow[j][c];
      a0[j] += wv * lo.x;
      a1[j] += wv * lo.y;
      a2[j] += wv * hi.x;
      a3[j] += wv * hi.y;
    }
  }
  int m = pr * 64 + pos;
#pragma unroll
  for (int j = 0; j < 9; j++) {
    int oc = oc0 + j;
    float v = fmaxf(fmaxf(a0[j], a1[j]), fmaxf(a2[j], a3[j]));
    if (oc < 64) gT[((size_t)b * 64 + oc) * NPOOL + m] = (__bf16)v;
    else         phiT[((size_t)b * NPOOL + m) * 8 + (oc - 64)] = (_Float16)v;
  }
}

// ---- K2: flash attention partials; shift-free bf16-P softmax; gl_lds staging ----
// grid = b(2) x qt(128) x kc(4) = 1024 blocks; 4 waves x 32 queries
__global__ __launch_bounds__(256, 4) void attn_kernel(
    const _Float16* __restrict__ qf, const _Float16* __restrict__ phiT,
    const __bf16* __restrict__ gT,
    float* __restrict__ part_l, _Float16* __restrict__ part_o) {
  __shared__ __bf16 lds_g[2][64 * 64];   // double buffer, 8 KB each
  int bx = blockIdx.x;
  int kc = bx & (KSPLIT - 1);
  int qt = (bx >> 2) & 127;
  int b  = bx >> 9;
  int tid = threadIdx.x;
  int lane = tid & 63;
  int w = tid >> 6;
  int q = lane & 31, hi = lane >> 5;
  int qg0 = qt * 128 + w * 32;
  size_t qrow = (size_t)b * NPIX + qg0 + q;

  half8 qfrag = {0, 0, 0, 0, 0, 0, 0, 0};
  if (!hi) qfrag = *(const half8*)(qf + qrow * 8);

  f32x16 oacc0, oacc1;
#pragma unroll
  for (int i = 0; i < 16; i++) { oacc0[i] = 0.f; oacc1[i] = 0.f; }
  float lsum = 0.f;

  int kb0 = kc * CHUNK;

  // gl_lds staging: linear LDS dest (base + lane*16), inverse-swizzled source.
  const __bf16* gbase0;
  const __bf16* gbase1;
  {
    int c0 = (w * 2 + 0) * 8 + (lane >> 3);
    int c1 = (w * 2 + 1) * 8 + (lane >> 3);
    int s  = (lane & 7) ^ (lane >> 3);
    gbase0 = gT + ((size_t)b * 64 + c0) * NPOOL + 8 * s;
    gbase1 = gT + ((size_t)b * 64 + c1) * NPOOL + 8 * s;
  }
#define STAGE(buf, kb)                                                        \
  do {                                                                        \
    __builtin_amdgcn_global_load_lds(                                         \
        (const __attribute__((address_space(1))) void*)(gbase0 + (kb)),       \
        (__attribute__((address_space(3))) void*)((char*)&lds_g[buf][0] +     \
                                                  (w * 2 + 0) * 1024),        \
        16, 0, 0);                                                            \
    __builtin_amdgcn_global_load_lds(                                         \
        (const __attribute__((address_space(1))) void*)(gbase1 + (kb)),       \
        (__attribute__((address_space(3))) void*)((char*)&lds_g[buf][0] +     \
                                                  (w * 2 + 1) * 1024),        \
        16, 0, 0);                                                            \
  } while (0)

  STAGE(0, kb0);
  __syncthreads();                       // buf0 visible
  int cur = 0;

#pragma unroll 1
  for (int step = 0; step < NSTEP; ++step) {
    int kb = kb0 + step * 64;
    if (step + 1 < NSTEP) STAGE(cur ^ 1, kb + 64);   // prefetch next tile
    half8 aphi0 = {0, 0, 0, 0, 0, 0, 0, 0}, aphi1 = aphi0;
    if (!hi) {
      aphi0 = *(const half8*)(phiT + ((size_t)b * NPOOL + kb + q) * 8);
      aphi1 = *(const half8*)(phiT + ((size_t)b * NPOOL + kb + 32 + q) * 8);
    }
    const __bf16* ldsb = &lds_g[cur][0];
#pragma unroll
    for (int sub = 0; sub < 2; ++sub) {
      half8 aphi = sub ? aphi1 : aphi0;
      f32x16 sacc;
#pragma unroll
      for (int i = 0; i < 16; i++) sacc[i] = 0.f;    // no shift needed (bf16 P)
      sacc = mfma16(aphi, qfrag, sacc);
      float p[16];
#pragma unroll
      for (int i = 0; i < 16; i++)
        p[i] = fast_exp2(fminf(sacc[i], 126.f));     // raw v_exp_f32 + inf guard
      lsum += (((p[0] + p[1]) + (p[2] + p[3])) + ((p[4] + p[5]) + (p[6] + p[7]))) +
              (((p[8] + p[9]) + (p[10] + p[11])) + ((p[12] + p[13]) + (p[14] + p[15])));
#pragma unroll
      for (int halfk = 0; halfk < 2; ++halfk) {
        int pb = halfk * 8;
        bf16x2v t0 = {(__bf16)p[pb + 0], (__bf16)p[pb + 1]};
        bf16x2v t1 = {(__bf16)p[pb + 2], (__bf16)p[pb + 3]};
        bf16x2v t2 = {(__bf16)p[pb + 4], (__bf16)p[pb + 5]};
        bf16x2v t3 = {(__bf16)p[pb + 6], (__bf16)p[pb + 7]};
        unsigned A0 = __builtin_bit_cast(unsigned, t0);
        unsigned A1 = __builtin_bit_cast(unsigned, t1);
        unsigned B0 = __builtin_bit_cast(unsigned, t2);
        unsigned B1 = __builtin_bit_cast(unsigned, t3);
        union { unsigned u[4]; bf16x8 h; } pf;
#if __has_builtin(__builtin_amdgcn_permlane32_swap)
        uint2v r0 = __builtin_amdgcn_permlane32_swap(A0, B0, false, false);
        uint2v r1 = __builtin_amdgcn_permlane32_swap(A1, B1, false, false);
        pf.u[0] = r0[0]; pf.u[1] = r1[0]; pf.u[2] = r0[1]; pf.u[3] = r1[1];
#else
        unsigned xA0 = __shfl_xor(A0, 32), xA1 = __shfl_xor(A1, 32);
        unsigned xB0 = __shfl_xor(B0, 32), xB1 = __shfl_xor(B1, 32);
        pf.u[0] = hi ? xB0 : A0;
        pf.u[1] = hi ? xB1 : A1;
        pf.u[2] = hi ? B0 : xA0;
        pf.u[3] = hi ? B1 : xA1;
#endif
        int sread = sub * 4 + halfk * 2 + hi;
        __builtin_amdgcn_s_setprio(1);
#pragma unroll
        for (int ct = 0; ct < 2; ++ct) {
          int row = ct * 32 + q;
          bf16x8 ag = *(const bf16x8*)(ldsb + row * 64 +
                                       (((16 * sread) ^ ((row & 7) << 4)) >> 1));
          if (ct == 0) oacc0 = mfma16b(ag, pf.h, oacc0);
          else         oacc1 = mfma16b(ag, pf.h, oacc1);
        }
        __builtin_amdgcn_s_setprio(0);
      }
    }
    if (step + 1 < NSTEP) { __syncthreads(); cur ^= 1; }  // uniform condition
  }
  lsum += __shfl_xor(lsum, 32);          // chunk-total l (both half-lanes)
  float rl = 1.0f / lsum;
  if (!hi) part_l[(size_t)kc * BN + qrow] = lsum;
  // part_o f16 layout [kc][b][n][64] holds NORMALIZED o/l; 8B packed stores
  _Float16* po = part_o + (((size_t)(kc * 2 + b) * NPIX) + qg0 + q) * 64;
#pragma unroll
  for (int ct = 0; ct < 2; ++ct) {
#pragma unroll
    for (int g = 0; g < 4; ++g) {
      float v0 = (ct ? oacc1[4 * g + 0] : oacc0[4 * g + 0]) * rl;
      float v1 = (ct ? oacc1[4 * g + 1] : oacc0[4 * g + 1]) * rl;
      float v2 = (ct ? oacc1[4 * g + 2] : oacc0[4 * g + 2]) * rl;
      float v3 = (ct ? oacc1[4 * g + 3] : oacc0[4 * g + 3]) * rl;
      uint2v u;
      u[0] = __builtin_bit_cast(unsigned, __builtin_amdgcn_cvt_pkrtz(v0, v1));
      u[1] = __builtin_bit_cast(unsigned, __builtin_amdgcn_cvt_pkrtz(v2, v3));
      *(uint2v*)(po + 32 * ct + 8 * g + 4 * hi) = u;   // ch = (r&3)+8g+4hi+32ct
    }
  }
}

// ---- K3: l-weighted combine + residual epilogue ----
__global__ __launch_bounds__(256) void reduce_kernel(
    const float* __restrict__ part_l, const _Float16* __restrict__ part_o,
    const float* __restrict__ x, const float* __restrict__ sig,
    float* __restrict__ out) {
  int t = threadIdx.x;
  int cg = t >> 6;                       // 0..3 -> channels cg*16..+15
  int qi = blockIdx.x * 64 + (t & 63);
  int b = qi >> 14, n = qi & (NPIX - 1);
  float lv[KSPLIT], L = 0.f;
#pragma unroll
  for (int kc = 0; kc < KSPLIT; kc++) {
    lv[kc] = part_l[(size_t)kc * BN + qi];
    L += lv[kc];
  }
  float o16[16];
#pragma unroll
  for (int j = 0; j < 16; j++) o16[j] = 0.f;
#pragma unroll
  for (int kc = 0; kc < KSPLIT; kc++) {
    const _Float16* po = part_o + (((size_t)(kc * 2 + b) * NPIX) + n) * 64 + cg * 16;
    f16x8 v0 = *(const f16x8*)po;
    f16x8 v1 = *(const f16x8*)(po + 8);
    float wv = lv[kc];
#pragma unroll
    for (int j = 0; j < 8; j++) {
      o16[j]     += wv * (float)v0[j];
      o16[8 + j] += wv * (float)v1[j];
    }
  }
  float scale = sig[0] / L;
#pragma unroll
  for (int j = 0; j < 16; j++) {
    int c = cg * 16 + j;
    size_t idx = ((size_t)b * 64 + c) * NPIX + n;
    out[idx] = x[idx] + scale * o16[j];
  }
}

extern "C" void kernel_launch(void* const* d_in, const int* in_sizes, int n_in,
                              void* d_out, int out_size, void* d_ws, size_t ws_size,
                              hipStream_t stream) {
  const float* x       = (const float*)d_in[0];
  const float* w_theta = (const float*)d_in[1];
  const float* b_theta = (const float*)d_in[2];
  const float* w_phi   = (const float*)d_in[3];
  const float* b_phi   = (const float*)d_in[4];
  const float* w_g     = (const float*)d_in[5];
  const float* b_g     = (const float*)d_in[6];
  const float* sigma   = (const float*)d_in[7];
  float* out = (float*)d_out;

  // Workspace layout (bytes):
  //   qf     @ 0        : BN*8*2              = 524288
  //   phiT   @ 524288   : 2*NPOOL*8*2         = 131072
  //   gT     @ 655360   : 2*64*NPOOL*2        = 1048576  (bf16)
  //   part_l @ 1703936  : KSPLIT*BN*4         = 524288
  //   part_o @ 2228224  : KSPLIT*2*NPIX*64*2  = 16777216   (total ~19 MB)
  char* ws = (char*)d_ws;
  _Float16* qf     = (_Float16*)ws;
  _Float16* phiT   = (_Float16*)(ws + 524288);
  __bf16*   gT     = (__bf16*)(ws + 655360);
  float*    part_l = (float*)(ws + 1703936);
  _Float16* part_o = (_Float16*)(ws + 2228224);

  prep_kernel<<<256, 256, 0, stream>>>(x, w_theta, b_theta, w_phi, b_phi,
                                       w_g, b_g, qf, phiT, gT);
  attn_kernel<<<2 * 128 * KSPLIT, 256, 0, stream>>>(qf, phiT, gT,
                                                    part_l, part_o);
  reduce_kernel<<<512, 256, 0, stream>>>(part_l, part_o, x, sigma, out);
}

// Round 15
// 63.801 us; speedup vs baseline: 2.3104x; 1.0560x over previous
//
#include <hip/hip_runtime.h>
#include <hip/hip_bf16.h>

typedef _Float16 half8 __attribute__((ext_vector_type(8)));
typedef _Float16 f16x8 __attribute__((ext_vector_type(8)));
typedef __fp16 fp16x2 __attribute__((ext_vector_type(2)));
typedef __bf16 bf16x2v __attribute__((ext_vector_type(2)));
typedef __bf16 bf16x8 __attribute__((ext_vector_type(8)));
typedef float f32x16 __attribute__((ext_vector_type(16)));
typedef unsigned uint2v __attribute__((ext_vector_type(2)));

#define NPIX 16384      // H*W
#define NPOOL 4096      // pooled N
#define BN 32768        // B*N
#define KSPLIT 4
#define CHUNK 1024      // NPOOL/KSPLIT
#define NSTEP 8         // CHUNK/128 (128 keys per barrier frame)
#define LOG2E 1.44269504088896340736f

__device__ inline f32x16 mfma16(half8 a, half8 b, f32x16 c) {
  return __builtin_amdgcn_mfma_f32_32x32x16_f16(a, b, c, 0, 0, 0);
}
__device__ inline f32x16 mfma16b(bf16x8 a, bf16x8 b, f32x16 c) {
  return __builtin_amdgcn_mfma_f32_32x32x16_bf16(a, b, c, 0, 0, 0);
}
__device__ inline float fast_exp2(float x) {
#if __has_builtin(__builtin_amdgcn_exp2f)
  return __builtin_amdgcn_exp2f(x);      // raw v_exp_f32 (1 inst, <=1 ulp)
#else
  return exp2f(x);
#endif
}

// ---- K1 (fused prep): theta f16 [BN][8]*log2e; phiT f16 [b][M][8]; gT bf16 [b][64][M]
__global__ __launch_bounds__(256) void prep_kernel(
    const float* __restrict__ x,
    const float* __restrict__ w_theta, const float* __restrict__ b_theta,
    const float* __restrict__ w_phi, const float* __restrict__ b_phi,
    const float* __restrict__ w_g, const float* __restrict__ b_g,
    _Float16* __restrict__ qf, _Float16* __restrict__ phiT,
    __bf16* __restrict__ gT) {
  __shared__ float xs[64][256];
  int bid = blockIdx.x;
  int oh = bid & 1;
  int pr = (bid >> 1) & 63;
  int b  = bid >> 7;
  int t = threadIdx.x;

  const float* xb = x + (size_t)b * 64 * NPIX + pr * 256;
#pragma unroll 8
  for (int c = 0; c < 64; c++) xs[c][t] = xb[(size_t)c * NPIX + t];
  __syncthreads();

  if (oh == 0) {
    float acc[8];
#pragma unroll
    for (int j = 0; j < 8; j++) acc[j] = b_theta[j];
#pragma unroll 4
    for (int c = 0; c < 64; c++) {
      float xv = xs[c][t];
#pragma unroll
      for (int j = 0; j < 8; j++) acc[j] += xv * w_theta[j * 64 + c];
    }
    half8 h;
#pragma unroll
    for (int j = 0; j < 8; j++) h[j] = (_Float16)(acc[j] * LOG2E);
    *(half8*)(qf + ((size_t)b * NPIX + pr * 256 + t) * 8) = h;
  }

  int pos = t & 63;
  int ocg = t >> 6;
  int oc0 = oh * 36 + ocg * 9;
  const float* wrow[9];
  float a0[9], a1[9], a2[9], a3[9];
#pragma unroll
  for (int j = 0; j < 9; j++) {
    int oc = oc0 + j;
    float bv;
    if (oc < 64) { wrow[j] = w_g + oc * 64; bv = b_g[oc]; }
    else         { wrow[j] = w_phi + (oc - 64) * 64; bv = b_phi[oc - 64]; }
    a0[j] = bv; a1[j] = bv; a2[j] = bv; a3[j] = bv;
  }
#pragma unroll 4
  for (int c = 0; c < 64; c++) {
    float2 lo = *(const float2*)&xs[c][2 * pos];
    float2 hi = *(const float2*)&xs[c][128 + 2 * pos];
#pragma unroll
    for (int j = 0; j < 9; j++) {
      float wv = wrow[j][c];
      a0[j] += wv * lo.x;
      a1[j] += wv * lo.y;
      a2[j] += wv * hi.x;
      a3[j] += wv * hi.y;
    }
  }
  int m = pr * 64 + pos;
#pragma unroll
  for (int j = 0; j < 9; j++) {
    int oc = oc0 + j;
    float v = fmaxf(fmaxf(a0[j], a1[j]), fmaxf(a2[j], a3[j]));
    if (oc < 64) gT[((size_t)b * 64 + oc) * NPOOL + m] = (__bf16)v;
    else         phiT[((size_t)b * NPOOL + m) * 8 + (oc - 64)] = (_Float16)v;
  }
}

// ---- K2: flash attention partials; shift-free bf16-P softmax; gl_lds staging ----
// grid = b(2) x qt(128) x kc(4) = 1024 blocks; 4 waves x 32 queries
__global__ __launch_bounds__(256, 4) void attn_kernel(
    const _Float16* __restrict__ qf, const _Float16* __restrict__ phiT,
    const __bf16* __restrict__ gT,
    float* __restrict__ part_l, _Float16* __restrict__ part_o) {
  __shared__ __bf16 lds_g[2][128 * 64];  // double buffer, 16 KB each (128 keys)
  int bx = blockIdx.x;
  int kc = bx & (KSPLIT - 1);
  int qt = (bx >> 2) & 127;
  int b  = bx >> 9;
  int tid = threadIdx.x;
  int lane = tid & 63;
  int w = tid >> 6;
  int q = lane & 31, hi = lane >> 5;
  int qg0 = qt * 128 + w * 32;
  size_t qrow = (size_t)b * NPIX + qg0 + q;

  half8 qfrag = {0, 0, 0, 0, 0, 0, 0, 0};
  if (!hi) qfrag = *(const half8*)(qf + qrow * 8);

  f32x16 oacc0, oacc1;
#pragma unroll
  for (int i = 0; i < 16; i++) { oacc0[i] = 0.f; oacc1[i] = 0.f; }
  float lsum = 0.f;

  int kb0 = kc * CHUNK;

  // gl_lds staging: linear LDS dest (base + lane*16), inverse-swizzled source.
  const __bf16* gbase0;
  const __bf16* gbase1;
  {
    int c0 = (w * 2 + 0) * 8 + (lane >> 3);
    int c1 = (w * 2 + 1) * 8 + (lane >> 3);
    int s  = (lane & 7) ^ (lane >> 3);
    gbase0 = gT + ((size_t)b * 64 + c0) * NPOOL + 8 * s;
    gbase1 = gT + ((size_t)b * 64 + c1) * NPOOL + 8 * s;
  }
  // stage 128 keys = two 64-key subtiles (sb): subtile sb at byte offset sb*8192
#define STAGE(buf, kb)                                                        \
  do {                                                                        \
    __builtin_amdgcn_global_load_lds(                                         \
        (const __attribute__((address_space(1))) void*)(gbase0 + (kb)),       \
        (__attribute__((address_space(3))) void*)((char*)&lds_g[buf][0] +     \
                                                  (w * 2 + 0) * 1024),        \
        16, 0, 0);                                                            \
    __builtin_amdgcn_global_load_lds(                                         \
        (const __attribute__((address_space(1))) void*)(gbase1 + (kb)),       \
        (__attribute__((address_space(3))) void*)((char*)&lds_g[buf][0] +     \
                                                  (w * 2 + 1) * 1024),        \
        16, 0, 0);                                                            \
    __builtin_amdgcn_global_load_lds(                                         \
        (const __attribute__((address_space(1))) void*)(gbase0 + (kb) + 64),  \
        (__attribute__((address_space(3))) void*)((char*)&lds_g[buf][0] +     \
                                                  8192 + (w * 2 + 0) * 1024), \
        16, 0, 0);                                                            \
    __builtin_amdgcn_global_load_lds(                                         \
        (const __attribute__((address_space(1))) void*)(gbase1 + (kb) + 64),  \
        (__attribute__((address_space(3))) void*)((char*)&lds_g[buf][0] +     \
                                                  8192 + (w * 2 + 1) * 1024), \
        16, 0, 0);                                                            \
  } while (0)

  STAGE(0, kb0);
  __syncthreads();                       // buf0 visible
  int cur = 0;

#pragma unroll 1
  for (int step = 0; step < NSTEP; ++step) {
    int kb = kb0 + step * 128;
    if (step + 1 < NSTEP) STAGE(cur ^ 1, kb + 128);  // prefetch next 128 keys
#pragma unroll
    for (int kk = 0; kk < 2; ++kk) {
      int kbb = kb + kk * 64;
      half8 aphi0 = {0, 0, 0, 0, 0, 0, 0, 0}, aphi1 = aphi0;
      if (!hi) {
        aphi0 = *(const half8*)(phiT + ((size_t)b * NPOOL + kbb + q) * 8);
        aphi1 = *(const half8*)(phiT + ((size_t)b * NPOOL + kbb + 32 + q) * 8);
      }
      const __bf16* ldsb = &lds_g[cur][kk * 4096];
#pragma unroll
      for (int sub = 0; sub < 2; ++sub) {
        half8 aphi = sub ? aphi1 : aphi0;
        f32x16 sacc;
#pragma unroll
        for (int i = 0; i < 16; i++) sacc[i] = 0.f;  // no shift needed (bf16 P)
        sacc = mfma16(aphi, qfrag, sacc);
        float p[16];
#pragma unroll
        for (int i = 0; i < 16; i++) p[i] = fast_exp2(sacc[i]);
        lsum += (((p[0] + p[1]) + (p[2] + p[3])) + ((p[4] + p[5]) + (p[6] + p[7]))) +
                (((p[8] + p[9]) + (p[10] + p[11])) + ((p[12] + p[13]) + (p[14] + p[15])));
#pragma unroll
        for (int halfk = 0; halfk < 2; ++halfk) {
          int pb = halfk * 8;
          bf16x2v t0 = {(__bf16)p[pb + 0], (__bf16)p[pb + 1]};
          bf16x2v t1 = {(__bf16)p[pb + 2], (__bf16)p[pb + 3]};
          bf16x2v t2 = {(__bf16)p[pb + 4], (__bf16)p[pb + 5]};
          bf16x2v t3 = {(__bf16)p[pb + 6], (__bf16)p[pb + 7]};
          unsigned A0 = __builtin_bit_cast(unsigned, t0);
          unsigned A1 = __builtin_bit_cast(unsigned, t1);
          unsigned B0 = __builtin_bit_cast(unsigned, t2);
          unsigned B1 = __builtin_bit_cast(unsigned, t3);
          union { unsigned u[4]; bf16x8 h; } pf;
#if __has_builtin(__builtin_amdgcn_permlane32_swap)
          uint2v r0 = __builtin_amdgcn_permlane32_swap(A0, B0, false, false);
          uint2v r1 = __builtin_amdgcn_permlane32_swap(A1, B1, false, false);
          pf.u[0] = r0[0]; pf.u[1] = r1[0]; pf.u[2] = r0[1]; pf.u[3] = r1[1];
#else
          unsigned xA0 = __shfl_xor(A0, 32), xA1 = __shfl_xor(A1, 32);
          unsigned xB0 = __shfl_xor(B0, 32), xB1 = __shfl_xor(B1, 32);
          pf.u[0] = hi ? xB0 : A0;
          pf.u[1] = hi ? xB1 : A1;
          pf.u[2] = hi ? B0 : xA0;
          pf.u[3] = hi ? B1 : xA1;
#endif
          int sread = sub * 4 + halfk * 2 + hi;
          __builtin_amdgcn_s_setprio(1);
#pragma unroll
          for (int ct = 0; ct < 2; ++ct) {
            int row = ct * 32 + q;
            bf16x8 ag = *(const bf16x8*)(ldsb + row * 64 +
                                         (((16 * sread) ^ ((row & 7) << 4)) >> 1));
            if (ct == 0) oacc0 = mfma16b(ag, pf.h, oacc0);
            else         oacc1 = mfma16b(ag, pf.h, oacc1);
          }
          __builtin_amdgcn_s_setprio(0);
        }
      }
    }
    if (step + 1 < NSTEP) { __syncthreads(); cur ^= 1; }  // uniform condition
  }
  lsum += __shfl_xor(lsum, 32);          // chunk-total l (both half-lanes)
  float rl = 1.0f / lsum;
  if (!hi) part_l[(size_t)kc * BN + qrow] = lsum;
  // part_o f16 layout [kc][b][n][64] holds NORMALIZED o/l; 8B packed stores
  _Float16* po = part_o + (((size_t)(kc * 2 + b) * NPIX) + qg0 + q) * 64;
#pragma unroll
  for (int ct = 0; ct < 2; ++ct) {
#pragma unroll
    for (int g = 0; g < 4; ++g) {
      float v0 = (ct ? oacc1[4 * g + 0] : oacc0[4 * g + 0]) * rl;
      float v1 = (ct ? oacc1[4 * g + 1] : oacc0[4 * g + 1]) * rl;
      float v2 = (ct ? oacc1[4 * g + 2] : oacc0[4 * g + 2]) * rl;
      float v3 = (ct ? oacc1[4 * g + 3] : oacc0[4 * g + 3]) * rl;
      uint2v u;
      u[0] = __builtin_bit_cast(unsigned, __builtin_amdgcn_cvt_pkrtz(v0, v1));
      u[1] = __builtin_bit_cast(unsigned, __builtin_amdgcn_cvt_pkrtz(v2, v3));
      *(uint2v*)(po + 32 * ct + 8 * g + 4 * hi) = u;   // ch = (r&3)+8g+4hi+32ct
    }
  }
}

// ---- K3: l-weighted combine + residual epilogue ----
__global__ __launch_bounds__(256) void reduce_kernel(
    const float* __restrict__ part_l, const _Float16* __restrict__ part_o,
    const float* __restrict__ x, const float* __restrict__ sig,
    float* __restrict__ out) {
  int t = threadIdx.x;
  int cg = t >> 6;                       // 0..3 -> channels cg*16..+15
  int qi = blockIdx.x * 64 + (t & 63);
  int b = qi >> 14, n = qi & (NPIX - 1);
  float lv[KSPLIT], L = 0.f;
#pragma unroll
  for (int kc = 0; kc < KSPLIT; kc++) {
    lv[kc] = part_l[(size_t)kc * BN + qi];
    L += lv[kc];
  }
  float o16[16];
#pragma unroll
  for (int j = 0; j < 16; j++) o16[j] = 0.f;
#pragma unroll
  for (int kc = 0; kc < KSPLIT; kc++) {
    const _Float16* po = part_o + (((size_t)(kc * 2 + b) * NPIX) + n) * 64 + cg * 16;
    f16x8 v0 = *(const f16x8*)po;
    f16x8 v1 = *(const f16x8*)(po + 8);
    float wv = lv[kc];
#pragma unroll
    for (int j = 0; j < 8; j++) {
      o16[j]     += wv * (float)v0[j];
      o16[8 + j] += wv * (float)v1[j];
    }
  }
  float scale = sig[0] / L;
#pragma unroll
  for (int j = 0; j < 16; j++) {
    int c = cg * 16 + j;
    size_t idx = ((size_t)b * 64 + c) * NPIX + n;
    out[idx] = x[idx] + scale * o16[j];
  }
}

extern "C" void kernel_launch(void* const* d_in, const int* in_sizes, int n_in,
                              void* d_out, int out_size, void* d_ws, size_t ws_size,
                              hipStream_t stream) {
  const float* x       = (const float*)d_in[0];
  const float* w_theta = (const float*)d_in[1];
  const float* b_theta = (const float*)d_in[2];
  const float* w_phi   = (const float*)d_in[3];
  const float* b_phi   = (const float*)d_in[4];
  const float* w_g     = (const float*)d_in[5];
  const float* b_g     = (const float*)d_in[6];
  const float* sigma   = (const float*)d_in[7];
  float* out = (float*)d_out;

  // Workspace layout (bytes):
  //   qf     @ 0        : BN*8*2              = 524288
  //   phiT   @ 524288   : 2*NPOOL*8*2         = 131072
  //   gT     @ 655360   : 2*64*NPOOL*2        = 1048576  (bf16)
  //   part_l @ 1703936  : KSPLIT*BN*4         = 524288
  //   part_o @ 2228224  : KSPLIT*2*NPIX*64*2  = 16777216   (total ~19 MB)
  char* ws = (char*)d_ws;
  _Float16* qf     = (_Float16*)ws;
  _Float16* phiT   = (_Float16*)(ws + 524288);
  __bf16*   gT     = (__bf16*)(ws + 655360);
  float*    part_l = (float*)(ws + 1703936);
  _Float16* part_o = (_Float16*)(ws + 2228224);

  prep_kernel<<<256, 256, 0, stream>>>(x, w_theta, b_theta, w_phi, b_phi,
                                       w_g, b_g, qf, phiT, gT);
  attn_kernel<<<2 * 128 * KSPLIT, 256, 0, stream>>>(qf, phiT, gT,
                                                    part_l, part_o);
  reduce_kernel<<<512, 256, 0, stream>>>(part_l, part_o, x, sigma, out);
}